// Round 3
// baseline (932.328 us; speedup 1.0000x reference)
//
#include <hip/hip_runtime.h>

typedef unsigned short u16;
typedef __attribute__((ext_vector_type(8))) short bf16x8;
typedef __attribute__((ext_vector_type(4))) float f32x4;
typedef __attribute__((ext_vector_type(4))) u16 u16x4;

#define DEV static __device__ __forceinline__

DEV u16 f2bf(float f) {
  union { float f; unsigned u; } v; v.f = f;
  unsigned r = (v.u + 0x7fffu + ((v.u >> 16) & 1u)) >> 16;
  return (u16)r;
}

DEV void gload_lds16(const void* g, void* l) {
  __builtin_amdgcn_global_load_lds(
      (const __attribute__((address_space(1))) unsigned int*)g,
      (__attribute__((address_space(3))) unsigned int*)l, 16, 0, 0);
}

// sum over each aligned 16-lane group via DPP row rotations (pure VALU)
DEV float rowsum16(float p) {
  p += __int_as_float(__builtin_amdgcn_update_dpp(0, __float_as_int(p), 0x128, 0xF, 0xF, true)); // ror:8
  p += __int_as_float(__builtin_amdgcn_update_dpp(0, __float_as_int(p), 0x124, 0xF, 0xF, true)); // ror:4
  p += __int_as_float(__builtin_amdgcn_update_dpp(0, __float_as_int(p), 0x122, 0xF, 0xF, true)); // ror:2
  p += __int_as_float(__builtin_amdgcn_update_dpp(0, __float_as_int(p), 0x121, 0xF, 0xF, true)); // ror:1
  return p;
}

// ---------------------------------------------------------------------------
// 256x256 8-wave MFMA GEMM, 4-phase-per-K-tile counted-vmcnt pipeline (m201
// structure). C[M,N] = A[M,K] * BT[N,K]^T. M == 2048 (8 row-tiles), N%256==0,
// K%64==0. 512 threads = 8 waves (2M x 4N); per-wave output 128x64.
// LDS: 2 buffers x (A[256][64] + B[256][64]) bf16 = 128 KiB, XOR-swizzled
// (chunk ^= row&7; linear gload_lds dest, inverse-swizzled global source).
// Per K-tile: stage order B01,B23,Ac01,Ac23 (1 half-tile / phase) into nxt;
// vmcnt(4) @phase1 (forces cur tile's A-c23), vmcnt(2) @phase3 (forces next
// tile's B + A-c01). EPI: 0 f32; 1 +bias,softplus f32; 2 f32 + bf16.
// ---------------------------------------------------------------------------
#define STG(buf, mat, rr, P, kt) gload_lds16( \
    (P) + (size_t)((rr) * 64 + srow) * K + (kt) + cg8, \
    &lds[buf][mat][(rr) * 64 + srow][sc8])
#define LDB() _Pragma("unroll") for (int n = 0; n < 4; ++n) { \
    const int row = wn * 64 + n * 16 + lr; \
    _Pragma("unroll") for (int kk = 0; kk < 2; ++kk) \
      bfr[n][kk] = *(const bf16x8*)&lds[cur][1][row][(((kk << 2) | lq) ^ (lr & 7)) << 3]; }
#define LDA(p) _Pragma("unroll") for (int mi = 0; mi < 2; ++mi) { \
    const int row = wm * 128 + ((p) * 2 + mi) * 16 + lr; \
    _Pragma("unroll") for (int kk = 0; kk < 2; ++kk) \
      af[mi][kk] = *(const bf16x8*)&lds[cur][0][row][(((kk << 2) | lq) ^ (lr & 7)) << 3]; }
#define MM(p) __builtin_amdgcn_s_setprio(1); \
  _Pragma("unroll") for (int kk = 0; kk < 2; ++kk) \
  _Pragma("unroll") for (int mi = 0; mi < 2; ++mi) \
  _Pragma("unroll") for (int n = 0; n < 4; ++n) \
    acc[(p) * 2 + mi][n] = __builtin_amdgcn_mfma_f32_16x16x32_bf16(af[mi][kk], bfr[n][kk], acc[(p) * 2 + mi][n], 0, 0, 0); \
  __builtin_amdgcn_s_setprio(0);
#define BAR() { __builtin_amdgcn_s_barrier(); asm volatile("" ::: "memory"); }
#define WLG() asm volatile("s_waitcnt lgkmcnt(0)" ::: "memory")

template<int EPI>
__global__ __launch_bounds__(512, 1)
void gemm256(const u16* __restrict__ A, const u16* __restrict__ BT,
             float* __restrict__ C, u16* __restrict__ Cbf,
             const float* __restrict__ bias, int M, int N, int K) {
  __shared__ u16 lds[2][2][256][64];
  const int t = threadIdx.x;
  const int l = t & 63;
  const int w = t >> 6;
  const int wm = w >> 2;        // 0..1
  const int wn = w & 3;         // 0..3
  const int lr = l & 15, lq = l >> 4;

  // bijective XCD-chunked swizzle; gridDim.x == 8 (M-tiles), nwg % 8 == 0
  const int gn = N >> 8;
  const int nwg = gn << 3;
  const int orig = blockIdx.y * 8 + blockIdx.x;
  const int q = nwg >> 3;
  const int swz = (orig & 7) * q + (orig >> 3);
  const int bx = swz & 7;
  const int by = swz >> 3;

  const u16* Ap = A + (size_t)bx * 256 * K;
  const u16* Bp = BT + (size_t)by * 256 * K;
  const int srow = t >> 3, schk = t & 7;
  const int sc8 = schk << 3;
  const int cg8 = (schk ^ (srow & 7)) << 3;

  f32x4 acc[8][4];
#pragma unroll
  for (int m = 0; m < 8; ++m)
#pragma unroll
    for (int n = 0; n < 4; ++n) acc[m][n] = (f32x4){0.f, 0.f, 0.f, 0.f};

  const int NT = K >> 6;
  // prologue: tile 0 -> buf 0 (same per-wave issue order as steady state)
  STG(0, 1, 0, Bp, 0); STG(0, 1, 1, Bp, 0); STG(0, 1, 2, Bp, 0); STG(0, 1, 3, Bp, 0);
  STG(0, 0, 0, Ap, 0); STG(0, 0, 2, Ap, 0); STG(0, 0, 1, Ap, 0); STG(0, 0, 3, Ap, 0);
  asm volatile("s_waitcnt vmcnt(2)" ::: "memory");
  BAR();

  for (int tt = 0; tt < NT; ++tt) {
    const int cur = tt & 1, nxt = cur ^ 1;
    const int ktn = (tt + 1) << 6;
    const bool more = tt + 1 < NT;
    bf16x8 bfr[4][2], af[2][2];
    // ---- phase 0: all B frags + A m-pair 0; stage next B rows 0-127 ----
    LDB(); LDA(0);
    if (more) { STG(nxt, 1, 0, Bp, ktn); STG(nxt, 1, 1, Bp, ktn); }
    BAR(); WLG();
    MM(0);
    BAR();
    // ---- phase 1: A m-pair 1; stage next B rows 128-255; vmcnt(4) ----
    LDA(1);
    if (more) {
      STG(nxt, 1, 2, Bp, ktn); STG(nxt, 1, 3, Bp, ktn);
      asm volatile("s_waitcnt vmcnt(4)" ::: "memory");
    } else {
      asm volatile("s_waitcnt vmcnt(0)" ::: "memory");
    }
    BAR(); WLG();
    MM(1);
    BAR();
    // ---- phase 2: A m-pair 2; stage next A chunk01 (both halves) ----
    LDA(2);
    if (more) { STG(nxt, 0, 0, Ap, ktn); STG(nxt, 0, 2, Ap, ktn); }
    BAR(); WLG();
    MM(2);
    BAR();
    // ---- phase 3: A m-pair 3; stage next A chunk23; vmcnt(2) ----
    LDA(3);
    if (more) {
      STG(nxt, 0, 1, Ap, ktn); STG(nxt, 0, 3, Ap, ktn);
      asm volatile("s_waitcnt vmcnt(2)" ::: "memory");
    }
    BAR(); WLG();
    MM(3);
    BAR();
  }

  const int lg4 = lq * 4;
#pragma unroll
  for (int m = 0; m < 8; ++m) {
    const int grow0 = bx * 256 + wm * 128 + m * 16 + lg4;
#pragma unroll
    for (int n = 0; n < 4; ++n) {
      const int gcol = by * 256 + wn * 64 + n * 16 + lr;
      float bv = 0.f;
      if (EPI == 1) bv = bias[gcol];
#pragma unroll
      for (int r = 0; r < 4; ++r) {
        float v = acc[m][n][r];
        if (EPI == 1) {
          v += bv;
          v = fmaxf(v, 0.f) + log1pf(expf(-fabsf(v)));   // stable softplus
        }
        const size_t idx = (size_t)(grow0 + r) * N + gcol;
        C[idx] = v;
        if (EPI == 2) Cbf[idx] = f2bf(v);
      }
    }
  }
}
#undef STG
#undef LDB
#undef LDA
#undef MM
#undef BAR
#undef WLG

// ---------------------------------------------------------------------------
// 128x128 BK=64 GEMM (kept for x_proj only: N=128, 16 blocks, latency-bound).
// EPI: 3 = f32 + bf16 of cols<64 into Cbf with row stride 64 (fused dt).
// ---------------------------------------------------------------------------
template<int EPI>
__global__ __launch_bounds__(256)
void gemm_bt(const u16* __restrict__ A, const u16* __restrict__ BT,
             float* __restrict__ C, u16* __restrict__ Cbf,
             const float* __restrict__ bias, int M, int N, int K) {
  __shared__ u16 As[128][64];
  __shared__ u16 Bs[128][64];
  const int t = threadIdx.x;
  const int l = t & 63;
  const int w = t >> 6;
  const int wr = (w >> 1) * 64;
  const int wc = (w & 1) * 64;

  const int nwg = gridDim.x * gridDim.y;
  const int orig = blockIdx.y * gridDim.x + blockIdx.x;
  const int swz = (orig & 7) * (nwg >> 3) + (orig >> 3);
  const int bx = swz & 15;
  const int by = swz >> 4;

  const size_t aoff = (size_t)bx * 128 * K;
  const size_t boff = (size_t)by * 128 * K;
  const int r0 = t >> 3;
  const int c0s = (((t & 7) ^ (r0 & 7)) << 3);
  const int c0l = (t & 7) << 3;
  const int lr = l & 15;
  const int lq = l >> 4;

  f32x4 acc[4][4];
#pragma unroll
  for (int i = 0; i < 4; ++i)
#pragma unroll
    for (int j = 0; j < 4; ++j) acc[i][j] = (f32x4){0.f, 0.f, 0.f, 0.f};

  for (int kt = 0; kt < K; kt += 64) {
    __syncthreads();
#pragma unroll
    for (int i = 0; i < 4; ++i) {
      const int r = r0 + i * 32;
      gload_lds16(A + aoff + (size_t)r * K + kt + c0s, &As[r][c0l]);
      gload_lds16(BT + boff + (size_t)r * K + kt + c0s, &Bs[r][c0l]);
    }
    __syncthreads();
#pragma unroll
    for (int kk = 0; kk < 2; ++kk) {
      bf16x8 af[4], bfr[4];
#pragma unroll
      for (int i = 0; i < 4; ++i) {
        const int row = wr + i * 16 + lr;
        af[i] = *(const bf16x8*)&As[row][(((kk << 2) | lq) ^ (row & 7)) << 3];
      }
#pragma unroll
      for (int j = 0; j < 4; ++j) {
        const int row = wc + j * 16 + lr;
        bfr[j] = *(const bf16x8*)&Bs[row][(((kk << 2) | lq) ^ (row & 7)) << 3];
      }
#pragma unroll
      for (int i = 0; i < 4; ++i)
#pragma unroll
        for (int j = 0; j < 4; ++j)
          acc[i][j] = __builtin_amdgcn_mfma_f32_16x16x32_bf16(af[i], bfr[j], acc[i][j], 0, 0, 0);
    }
  }

  const int lg4 = lq * 4;
#pragma unroll
  for (int i = 0; i < 4; ++i) {
    const int grow0 = bx * 128 + wr + i * 16 + lg4;
#pragma unroll
    for (int j = 0; j < 4; ++j) {
      const int gcol = by * 128 + wc + j * 16 + lr;
#pragma unroll
      for (int r = 0; r < 4; ++r) {
        float v = acc[i][j][r];
        const size_t idx = (size_t)(grow0 + r) * N + gcol;
        C[idx] = v;
        if (EPI == 3 && gcol < 64) Cbf[(size_t)(grow0 + r) * 64 + gcol] = f2bf(v);
      }
    }
  }
}

// ---------------------------------------------------------------------------
// batched transpose+convert: f32 (K,N) -> bf16 (Npad,K), zero-pad n>=N.
// ---------------------------------------------------------------------------
struct TBatch {
  const float* src[5];
  u16* dst[5];
  int K[5], N[5], tx[5];
  int start[6];
  int njobs;
};

__global__ __launch_bounds__(256)
void transpose_batch(TBatch tb) {
  const int tile = blockIdx.x;
  int j = 0;
  while (j + 1 < tb.njobs && tile >= tb.start[j + 1]) ++j;
  const int lt = tile - tb.start[j];
  const int K = tb.K[j];
  const int N = tb.N[j];
  const int kb = (lt % tb.tx[j]) * 32;
  const int nb = (lt / tb.tx[j]) * 32;
  const float* __restrict__ in = tb.src[j];
  u16* __restrict__ out = tb.dst[j];

  __shared__ float tile_s[32][33];
  const int tx = threadIdx.x & 31;
  const int ty = threadIdx.x >> 5;
#pragma unroll
  for (int s = 0; s < 4; ++s) {
    const int k = kb + ty + s * 8;
    const int n = nb + tx;
    tile_s[ty + s * 8][tx] = (n < N) ? in[(size_t)k * N + n] : 0.f;
  }
  __syncthreads();
#pragma unroll
  for (int s = 0; s < 4; ++s) {
    const int n = nb + ty + s * 8;
    const int k = kb + tx;
    out[(size_t)n * K + k] = f2bf(tile_s[tx][ty + s * 8]);
  }
}

__global__ __launch_bounds__(256)
void embed_gather(const int* __restrict__ ids, const float* __restrict__ embed,
                  u16* __restrict__ xbf) {
  const int r = blockIdx.x;
  const int c = threadIdx.x * 4;
  const int id = ids[r];
  const float4 v = *(const float4*)(embed + (size_t)id * 1024 + c);
  u16x4 o = { f2bf(v.x), f2bf(v.y), f2bf(v.z), f2bf(v.w) };
  *(u16x4*)(xbf + (size_t)r * 1024 + c) = o;
}

// u = silu(causal_conv(xin) + cb); writes f32 and bf16.  idx = r*2048+d
__global__ __launch_bounds__(256)
void conv_silu(const float* __restrict__ xz, const float* __restrict__ cw,
               const float* __restrict__ cb, float* __restrict__ u,
               u16* __restrict__ ubf) {
  const int idx = blockIdx.x * 256 + threadIdx.x;
  const int d = idx & 2047;
  const int r = idx >> 11;
  const int t = r & 1023;
  const float4 wv = *(const float4*)(cw + d * 4);
  float a = cb[d];
  if (t >= 3) {
    const float* p = xz + (size_t)(r - 3) * 4096 + d;
    a += p[0] * wv.x + p[4096] * wv.y + p[8192] * wv.z + p[12288] * wv.w;
  } else {
    const float wk[4] = { wv.x, wv.y, wv.z, wv.w };
#pragma unroll
    for (int k = 0; k < 4; ++k) {
      const int tt = t - 3 + k;
      if (tt >= 0) a += xz[(size_t)(r - 3 + k) * 4096 + d] * wk[k];
    }
  }
  const float s = a / (1.f + __expf(-a));
  u[idx] = s;
  ubf[idx] = f2bf(s);
}

// ---------------------------------------------------------------------------
// chunked selective scan: 8 chunks x 128 steps (pass1 local, pass2 global+y)
// ---------------------------------------------------------------------------
__global__ __launch_bounds__(256)
void scan_pass1(const float* __restrict__ delta, const float* __restrict__ u,
                const float* __restrict__ dbc, const float* __restrict__ A_log,
                float* __restrict__ Pb, float* __restrict__ Qb) {
  const int blk = blockIdx.x;
  const int ch = blk & 7;
  const int dt16 = (blk >> 3) & 127;
  const int b = blk >> 10;
  const int n = threadIdx.x & 15;
  const int dl = threadIdx.x >> 4;
  const int d = dt16 * 16 + dl;
  const float Ac = -expf(A_log[d * 16 + n]) * 1.44269504f;
  const int r0 = b * 1024 + ch * 128;
  float P = 1.f, h = 0.f;
  for (int j = 0; j < 128; ++j) {
    const size_t r = r0 + j;
    const float dlt = delta[r * 2048 + d];
    const float uu = u[r * 2048 + d];
    const float Bv = dbc[r * 128 + 64 + n];
    const float da = exp2f(dlt * Ac);
    P *= da;
    h = fmaf(da, h, dlt * uu * Bv);
  }
  const size_t idx = ((size_t)(b * 2048 + d) * 16 + n) * 8 + ch;
  Pb[idx] = P;
  Qb[idx] = h;
}

__global__ __launch_bounds__(256)
void scan_pass2(const float* __restrict__ delta, const float* __restrict__ u,
                const float* __restrict__ dbc, const float* __restrict__ xz,
                const float* __restrict__ A_log, const float* __restrict__ Dp,
                const float* __restrict__ Pb, const float* __restrict__ Qb,
                u16* __restrict__ ybf) {
  const int blk = blockIdx.x;
  const int ch = blk & 7;
  const int dt16 = (blk >> 3) & 127;
  const int b = blk >> 10;
  const int n = threadIdx.x & 15;
  const int dl = threadIdx.x >> 4;
  const int d = dt16 * 16 + dl;
  const float Ac = -expf(A_log[d * 16 + n]) * 1.44269504f;
  const float Dd = Dp[d];
  const int r0 = b * 1024 + ch * 128;

  float h = 0.f;
  const size_t p0 = ((size_t)(b * 2048 + d) * 16 + n) * 8;
  for (int cc = 0; cc < ch; ++cc) h = fmaf(Pb[p0 + cc], h, Qb[p0 + cc]);

  for (int j = 0; j < 128; ++j) {
    const size_t r = r0 + j;
    const float dlt = delta[r * 2048 + d];
    const float uu = u[r * 2048 + d];
    const float Bv = dbc[r * 128 + 64 + n];
    const float Cv = dbc[r * 128 + 80 + n];
    const float da = exp2f(dlt * Ac);
    h = fmaf(da, h, dlt * uu * Bv);
    float p = rowsum16(h * Cv);
    if (n == 0) {
      const float zz = xz[r * 4096 + 2048 + d];
      const float yv = (p + uu * Dd) * (zz / (1.f + __expf(-zz)));
      ybf[r * 2048 + d] = f2bf(yv);
    }
  }
}

// layernorm over 1024, writes bf16.  one wave per row; block = 4 rows.
__global__ __launch_bounds__(256)
void ln_bf(const float* __restrict__ x, const float* __restrict__ g,
           const float* __restrict__ b, u16* __restrict__ out) {
  const int r = blockIdx.x * 4 + (threadIdx.x >> 6);
  const int l = threadIdx.x & 63;
  const float4* xr = (const float4*)(x + (size_t)r * 1024);
  float4 v[4];
  float s = 0.f;
#pragma unroll
  for (int i = 0; i < 4; ++i) {
    v[i] = xr[i * 64 + l];
    s += v[i].x + v[i].y + v[i].z + v[i].w;
  }
#pragma unroll
  for (int m = 1; m < 64; m <<= 1) s += __shfl_xor(s, m, 64);
  const float mu = s * (1.f / 1024.f);
  float q = 0.f;
#pragma unroll
  for (int i = 0; i < 4; ++i) {
    float a0 = v[i].x - mu, a1 = v[i].y - mu, a2 = v[i].z - mu, a3 = v[i].w - mu;
    q += a0 * a0 + a1 * a1 + a2 * a2 + a3 * a3;
  }
#pragma unroll
  for (int m = 1; m < 64; m <<= 1) q += __shfl_xor(q, m, 64);
  const float rs = rsqrtf(q * (1.f / 1024.f) + 1e-5f);
#pragma unroll
  for (int i = 0; i < 4; ++i) {
    const int c = (i * 64 + l) * 4;
    const float4 gv = *(const float4*)(g + c);
    const float4 bv = *(const float4*)(b + c);
    u16x4 o = { f2bf((v[i].x - mu) * rs * gv.x + bv.x),
                f2bf((v[i].y - mu) * rs * gv.y + bv.y),
                f2bf((v[i].z - mu) * rs * gv.z + bv.z),
                f2bf((v[i].w - mu) * rs * gv.w + bv.w) };
    *(u16x4*)(out + (size_t)r * 1024 + c) = o;
  }
}

// ---------------------------------------------------------------------------
extern "C" void kernel_launch(void* const* d_in, const int* in_sizes, int n_in,
                              void* d_out, int out_size, void* d_ws, size_t ws_size,
                              hipStream_t stream) {
  (void)in_sizes; (void)n_in; (void)out_size; (void)ws_size;
  const int*   ids      = (const int*)d_in[0];
  const float* embed    = (const float*)d_in[1];
  const float* in_proj  = (const float*)d_in[2];
  const float* conv_w   = (const float*)d_in[3];
  const float* conv_b   = (const float*)d_in[4];
  const float* x_proj   = (const float*)d_in[5];
  const float* dt_w     = (const float*)d_in[6];
  const float* dt_b     = (const float*)d_in[7];
  const float* A_log    = (const float*)d_in[8];
  const float* Dp       = (const float*)d_in[9];
  const float* out_proj = (const float*)d_in[10];
  const float* ln_g     = (const float*)d_in[11];
  const float* ln_bta   = (const float*)d_in[12];
  const float* head     = (const float*)d_in[13];

  // f32 scratch inside d_out (all consumed before head GEMM overwrites)
  float* fout = (float*)d_out;
  float* xz   = fout;              // 2048*4096
  float* ubuf = fout + 8388608;    // 2048*2048
  float* dbuf = fout + 12582912;   // 2048*2048 (delta)
  float* dbc  = fout + 16777216;   // 2048*128
  float* xf   = fout + 17039360;   // 2048*1024
  float* Pb   = fout + 19136512;   // 524288
  float* Qb   = fout + 19660800;   // 524288

  // bf16 scratch in d_ws
  char* wp = (char*)d_ws;
  u16* headT = (u16*)wp; wp += (size_t)32000 * 1024 * 2;
  u16* WiT   = (u16*)wp; wp += (size_t)4096 * 1024 * 2;
  u16* WxT   = (u16*)wp; wp += (size_t)128 * 2048 * 2;
  u16* WdtT  = (u16*)wp; wp += (size_t)2048 * 64 * 2;
  u16* WoT   = (u16*)wp; wp += (size_t)1024 * 2048 * 2;
  u16* xbf   = (u16*)wp; wp += (size_t)2048 * 1024 * 2;
  u16* ubf   = (u16*)wp; wp += (size_t)2048 * 2048 * 2;
  u16* dtbf  = (u16*)wp; wp += (size_t)2048 * 64 * 2;
  u16* ybf   = (u16*)wp; wp += (size_t)2048 * 2048 * 2;
  u16* xlnbf = (u16*)wp; wp += (size_t)2048 * 1024 * 2;

  const dim3 tb(256);
  const dim3 tb5(512);
  embed_gather<<<2048, tb, 0, stream>>>(ids, embed, xbf);

  for (int i = 0; i < 2; ++i) {
    TBatch t{};
    int nj = 0, acc = 0;
    if (i == 0) {
      t.src[nj] = head; t.dst[nj] = headT;
      t.K[nj] = 1024; t.N[nj] = 32000; t.tx[nj] = 32;
      t.start[nj] = acc; acc += 32 * 1000; ++nj;
    }
    t.src[nj] = in_proj + (size_t)i * 1024 * 4096; t.dst[nj] = WiT;
    t.K[nj] = 1024; t.N[nj] = 4096; t.tx[nj] = 32;
    t.start[nj] = acc; acc += 32 * 128; ++nj;
    t.src[nj] = x_proj + (size_t)i * 2048 * 96; t.dst[nj] = WxT;
    t.K[nj] = 2048; t.N[nj] = 96; t.tx[nj] = 64;
    t.start[nj] = acc; acc += 64 * 4; ++nj;
    t.src[nj] = dt_w + (size_t)i * 64 * 2048; t.dst[nj] = WdtT;
    t.K[nj] = 64; t.N[nj] = 2048; t.tx[nj] = 2;
    t.start[nj] = acc; acc += 2 * 64; ++nj;
    t.src[nj] = out_proj + (size_t)i * 2048 * 1024; t.dst[nj] = WoT;
    t.K[nj] = 2048; t.N[nj] = 1024; t.tx[nj] = 64;
    t.start[nj] = acc; acc += 64 * 32; ++nj;
    t.start[nj] = acc;
    t.njobs = nj;
    transpose_batch<<<acc, tb, 0, stream>>>(t);

    gemm256<0><<<dim3(8, 16), tb5, 0, stream>>>(xbf, WiT, xz, nullptr, nullptr, 2048, 4096, 1024);
    conv_silu<<<16384, tb, 0, stream>>>(xz, conv_w + i * 2048 * 4, conv_b + i * 2048, ubuf, ubf);
    gemm_bt<3><<<dim3(16, 1), tb, 0, stream>>>(ubf, WxT, dbc, dtbf, nullptr, 2048, 128, 2048);
    gemm256<1><<<dim3(8, 8), tb5, 0, stream>>>(dtbf, WdtT, dbuf, nullptr, dt_b + i * 2048, 2048, 2048, 64);
    scan_pass1<<<2048, tb, 0, stream>>>(dbuf, ubuf, dbc, A_log + i * 2048 * 16, Pb, Qb);
    scan_pass2<<<2048, tb, 0, stream>>>(dbuf, ubuf, dbc, xz, A_log + i * 2048 * 16, Dp + i * 2048, Pb, Qb, ybf);
    gemm256<2><<<dim3(8, 4), tb5, 0, stream>>>(ybf, WoT, xf, xbf, nullptr, 2048, 1024, 2048);
  }

  ln_bf<<<512, tb, 0, stream>>>(xf, ln_g, ln_bta, xlnbf);
  gemm256<0><<<dim3(8, 125), tb5, 0, stream>>>(xlnbf, headT, fout, nullptr, nullptr, 2048, 32000, 1024);
}

// Round 4
// 818.346 us; speedup vs baseline: 1.1393x; 1.1393x over previous
//
#include <hip/hip_runtime.h>

typedef unsigned short u16;
typedef __attribute__((ext_vector_type(8))) short bf16x8;
typedef __attribute__((ext_vector_type(4))) float f32x4;
typedef __attribute__((ext_vector_type(4))) u16 u16x4;

#define DEV static __device__ __forceinline__

DEV u16 f2bf(float f) {
  union { float f; unsigned u; } v; v.f = f;
  unsigned r = (v.u + 0x7fffu + ((v.u >> 16) & 1u)) >> 16;
  return (u16)r;
}

DEV void gload_lds16(const void* g, void* l) {
  __builtin_amdgcn_global_load_lds(
      (const __attribute__((address_space(1))) unsigned int*)g,
      (__attribute__((address_space(3))) unsigned int*)l, 16, 0, 0);
}

// sum over each aligned 16-lane group via DPP row rotations (pure VALU)
DEV float rowsum16(float p) {
  p += __int_as_float(__builtin_amdgcn_update_dpp(0, __float_as_int(p), 0x128, 0xF, 0xF, true)); // ror:8
  p += __int_as_float(__builtin_amdgcn_update_dpp(0, __float_as_int(p), 0x124, 0xF, 0xF, true)); // ror:4
  p += __int_as_float(__builtin_amdgcn_update_dpp(0, __float_as_int(p), 0x122, 0xF, 0xF, true)); // ror:2
  p += __int_as_float(__builtin_amdgcn_update_dpp(0, __float_as_int(p), 0x121, 0xF, 0xF, true)); // ror:1
  return p;
}

// ---------------------------------------------------------------------------
// 256x256 8-wave MFMA GEMM, 4 phases per K-tile, ONE barrier per phase,
// counted vmcnt (never 0 mid-loop). Used for the HEAD GEMM only (grid must
// fill the GPU: N=32000 -> 1000 blocks). C[M,N] = A[M,K]*BT[N,K]^T.
// LDS: 2buf x (A[256][64] + B[256][64]) bf16 = 128 KiB, XOR-swizzled
// (chunk ^= row&7; linear gload_lds dest, inverse-swizzled global source).
// Stage order per tile into nxt: B01@ph0, B23@ph1, Ac02@ph2, Ac13@ph3.
// vmcnt(4)@ph1 forces cur tile's A chunks 1,3; vmcnt(2)@ph3 forces next
// tile's B + A chunks 0,2.  Single barrier/phase: publication = per-wave
// vmcnt -> barrier -> read; reads of buf complete before the reader's own
// MFMA, which precedes its next barrier arrival, so overwrite is safe.
// ---------------------------------------------------------------------------
#define STG(buf, mat, rr, P, kt) gload_lds16( \
    (P) + (size_t)((rr) * 64 + srow) * K + (kt) + cg8, \
    &lds[buf][mat][(rr) * 64 + srow][sc8])
#define LDB() _Pragma("unroll") for (int n = 0; n < 4; ++n) { \
    const int row = wn * 64 + n * 16 + lr; \
    _Pragma("unroll") for (int kk = 0; kk < 2; ++kk) \
      bfr[n][kk] = *(const bf16x8*)&lds[cur][1][row][(((kk << 2) | lq) ^ (lr & 7)) << 3]; }
#define LDA(p) _Pragma("unroll") for (int mi = 0; mi < 2; ++mi) { \
    const int row = wm * 128 + ((p) * 2 + mi) * 16 + lr; \
    _Pragma("unroll") for (int kk = 0; kk < 2; ++kk) \
      af[mi][kk] = *(const bf16x8*)&lds[cur][0][row][(((kk << 2) | lq) ^ (lr & 7)) << 3]; }
#define MM(p) __builtin_amdgcn_s_setprio(1); \
  _Pragma("unroll") for (int kk = 0; kk < 2; ++kk) \
  _Pragma("unroll") for (int mi = 0; mi < 2; ++mi) \
  _Pragma("unroll") for (int n = 0; n < 4; ++n) \
    acc[(p) * 2 + mi][n] = __builtin_amdgcn_mfma_f32_16x16x32_bf16(af[mi][kk], bfr[n][kk], acc[(p) * 2 + mi][n], 0, 0, 0); \
  __builtin_amdgcn_s_setprio(0);
#define BAR() { __builtin_amdgcn_s_barrier(); asm volatile("" ::: "memory"); }

template<int EPI>
__global__ __launch_bounds__(512, 1)
void gemm256(const u16* __restrict__ A, const u16* __restrict__ BT,
             float* __restrict__ C, u16* __restrict__ Cbf,
             const float* __restrict__ bias, int M, int N, int K) {
  __shared__ u16 lds[2][2][256][64];
  const int t = threadIdx.x;
  const int l = t & 63;
  const int w = t >> 6;
  const int wm = w >> 2;        // 0..1
  const int wn = w & 3;         // 0..3
  const int lr = l & 15, lq = l >> 4;

  // bijective XCD-chunked swizzle; gridDim.x == 8 (M-tiles), nwg % 8 == 0
  const int gn = N >> 8;
  const int nwg = gn << 3;
  const int orig = blockIdx.y * 8 + blockIdx.x;
  const int q = nwg >> 3;
  const int swz = (orig & 7) * q + (orig >> 3);
  const int bx = swz & 7;
  const int by = swz >> 3;

  const u16* Ap = A + (size_t)bx * 256 * K;
  const u16* Bp = BT + (size_t)by * 256 * K;
  const int srow = t >> 3, schk = t & 7;
  const int sc8 = schk << 3;
  const int cg8 = (schk ^ (srow & 7)) << 3;

  f32x4 acc[8][4];
#pragma unroll
  for (int m = 0; m < 8; ++m)
#pragma unroll
    for (int n = 0; n < 4; ++n) acc[m][n] = (f32x4){0.f, 0.f, 0.f, 0.f};

  const int NT = K >> 6;
  // prologue: tile 0 -> buf 0 (B all, A chunks 0,2 then 1,3)
  STG(0, 1, 0, Bp, 0); STG(0, 1, 1, Bp, 0); STG(0, 1, 2, Bp, 0); STG(0, 1, 3, Bp, 0);
  STG(0, 0, 0, Ap, 0); STG(0, 0, 2, Ap, 0); STG(0, 0, 1, Ap, 0); STG(0, 0, 3, Ap, 0);
  asm volatile("s_waitcnt vmcnt(2)" ::: "memory");

  for (int tt = 0; tt < NT; ++tt) {
    const int cur = tt & 1, nxt = cur ^ 1;
    const int ktn = (tt + 1) << 6;
    const bool more = tt + 1 < NT;
    bf16x8 bfr[4][2], af[2][2];
    // ---- phase 0: B frags + A m-pair 0; stage next B rows 0-127 ----
    BAR();
    if (more) { STG(nxt, 1, 0, Bp, ktn); STG(nxt, 1, 1, Bp, ktn); }
    LDB(); LDA(0);
    MM(0);
    // ---- phase 1: A m-pair 1; stage next B rows 128-255; vmcnt(4) ----
    BAR();
    if (more) {
      STG(nxt, 1, 2, Bp, ktn); STG(nxt, 1, 3, Bp, ktn);
      asm volatile("s_waitcnt vmcnt(4)" ::: "memory");
    } else {
      asm volatile("s_waitcnt vmcnt(0)" ::: "memory");
    }
    LDA(1);
    MM(1);
    // ---- phase 2: A m-pair 2; stage next A chunks 0,2 ----
    BAR();
    if (more) { STG(nxt, 0, 0, Ap, ktn); STG(nxt, 0, 2, Ap, ktn); }
    LDA(2);
    MM(2);
    // ---- phase 3: A m-pair 3; stage next A chunks 1,3; vmcnt(2) ----
    BAR();
    if (more) {
      STG(nxt, 0, 1, Ap, ktn); STG(nxt, 0, 3, Ap, ktn);
      asm volatile("s_waitcnt vmcnt(2)" ::: "memory");
    }
    LDA(3);
    MM(3);
  }

  const int lg4 = lq * 4;
#pragma unroll
  for (int m = 0; m < 8; ++m) {
    const int grow0 = bx * 256 + wm * 128 + m * 16 + lg4;
#pragma unroll
    for (int n = 0; n < 4; ++n) {
      const int gcol = by * 256 + wn * 64 + n * 16 + lr;
      float bv = 0.f;
      if (EPI == 1) bv = bias[gcol];
#pragma unroll
      for (int r = 0; r < 4; ++r) {
        float v = acc[m][n][r];
        if (EPI == 1) {
          v += bv;
          v = fmaxf(v, 0.f) + log1pf(expf(-fabsf(v)));
        }
        const size_t idx = (size_t)(grow0 + r) * N + gcol;
        C[idx] = v;
        if (EPI == 2) Cbf[idx] = f2bf(v);
      }
    }
  }
}
#undef STG
#undef LDB
#undef LDA
#undef MM
#undef BAR

// ---------------------------------------------------------------------------
// 128x128 BK=64 GEMM for the small-N GEMMs (fills the GPU with blocks).
// EPI: 0 = f32; 1 = +bias, softplus, f32; 2 = f32 + bf16; 3 = f32 + bf16 of
//      cols<64 into Cbf with row stride 64 (fused dt extract).
// gridDim.x MUST be 16; nwg % 8 == 0.
// ---------------------------------------------------------------------------
template<int EPI>
__global__ __launch_bounds__(256)
void gemm_bt(const u16* __restrict__ A, const u16* __restrict__ BT,
             float* __restrict__ C, u16* __restrict__ Cbf,
             const float* __restrict__ bias, int M, int N, int K) {
  __shared__ u16 As[128][64];
  __shared__ u16 Bs[128][64];
  const int t = threadIdx.x;
  const int l = t & 63;
  const int w = t >> 6;
  const int wr = (w >> 1) * 64;
  const int wc = (w & 1) * 64;

  const int nwg = gridDim.x * gridDim.y;
  const int orig = blockIdx.y * gridDim.x + blockIdx.x;
  const int swz = (orig & 7) * (nwg >> 3) + (orig >> 3);
  const int bx = swz & 15;
  const int by = swz >> 4;

  const size_t aoff = (size_t)bx * 128 * K;
  const size_t boff = (size_t)by * 128 * K;
  const int r0 = t >> 3;
  const int c0s = (((t & 7) ^ (r0 & 7)) << 3);
  const int c0l = (t & 7) << 3;
  const int lr = l & 15;
  const int lq = l >> 4;

  f32x4 acc[4][4];
#pragma unroll
  for (int i = 0; i < 4; ++i)
#pragma unroll
    for (int j = 0; j < 4; ++j) acc[i][j] = (f32x4){0.f, 0.f, 0.f, 0.f};

  for (int kt = 0; kt < K; kt += 64) {
    __syncthreads();
#pragma unroll
    for (int i = 0; i < 4; ++i) {
      const int r = r0 + i * 32;
      gload_lds16(A + aoff + (size_t)r * K + kt + c0s, &As[r][c0l]);
      gload_lds16(BT + boff + (size_t)r * K + kt + c0s, &Bs[r][c0l]);
    }
    __syncthreads();
#pragma unroll
    for (int kk = 0; kk < 2; ++kk) {
      bf16x8 af[4], bfr[4];
#pragma unroll
      for (int i = 0; i < 4; ++i) {
        const int row = wr + i * 16 + lr;
        af[i] = *(const bf16x8*)&As[row][(((kk << 2) | lq) ^ (row & 7)) << 3];
      }
#pragma unroll
      for (int j = 0; j < 4; ++j) {
        const int row = wc + j * 16 + lr;
        bfr[j] = *(const bf16x8*)&Bs[row][(((kk << 2) | lq) ^ (row & 7)) << 3];
      }
#pragma unroll
      for (int i = 0; i < 4; ++i)
#pragma unroll
        for (int j = 0; j < 4; ++j)
          acc[i][j] = __builtin_amdgcn_mfma_f32_16x16x32_bf16(af[i], bfr[j], acc[i][j], 0, 0, 0);
    }
  }

  const int lg4 = lq * 4;
#pragma unroll
  for (int i = 0; i < 4; ++i) {
    const int grow0 = bx * 128 + wr + i * 16 + lg4;
#pragma unroll
    for (int j = 0; j < 4; ++j) {
      const int gcol = by * 128 + wc + j * 16 + lr;
      float bv = 0.f;
      if (EPI == 1) bv = bias[gcol];
#pragma unroll
      for (int r = 0; r < 4; ++r) {
        float v = acc[i][j][r];
        if (EPI == 1) {
          v += bv;
          v = fmaxf(v, 0.f) + log1pf(expf(-fabsf(v)));   // stable softplus
        }
        const size_t idx = (size_t)(grow0 + r) * N + gcol;
        C[idx] = v;
        if (EPI == 2) Cbf[idx] = f2bf(v);
        if (EPI == 3 && gcol < 64) Cbf[(size_t)(grow0 + r) * 64 + gcol] = f2bf(v);
      }
    }
  }
}

// ---------------------------------------------------------------------------
// batched transpose+convert: f32 (K,N) -> bf16 (Npad,K), zero-pad n>=N.
// ---------------------------------------------------------------------------
struct TBatch {
  const float* src[5];
  u16* dst[5];
  int K[5], N[5], tx[5];
  int start[6];
  int njobs;
};

__global__ __launch_bounds__(256)
void transpose_batch(TBatch tb) {
  const int tile = blockIdx.x;
  int j = 0;
  while (j + 1 < tb.njobs && tile >= tb.start[j + 1]) ++j;
  const int lt = tile - tb.start[j];
  const int K = tb.K[j];
  const int N = tb.N[j];
  const int kb = (lt % tb.tx[j]) * 32;
  const int nb = (lt / tb.tx[j]) * 32;
  const float* __restrict__ in = tb.src[j];
  u16* __restrict__ out = tb.dst[j];

  __shared__ float tile_s[32][33];
  const int tx = threadIdx.x & 31;
  const int ty = threadIdx.x >> 5;
#pragma unroll
  for (int s = 0; s < 4; ++s) {
    const int k = kb + ty + s * 8;
    const int n = nb + tx;
    tile_s[ty + s * 8][tx] = (n < N) ? in[(size_t)k * N + n] : 0.f;
  }
  __syncthreads();
#pragma unroll
  for (int s = 0; s < 4; ++s) {
    const int n = nb + ty + s * 8;
    const int k = kb + tx;
    out[(size_t)n * K + k] = f2bf(tile_s[tx][ty + s * 8]);
  }
}

__global__ __launch_bounds__(256)
void embed_gather(const int* __restrict__ ids, const float* __restrict__ embed,
                  u16* __restrict__ xbf) {
  const int r = blockIdx.x;
  const int c = threadIdx.x * 4;
  const int id = ids[r];
  const float4 v = *(const float4*)(embed + (size_t)id * 1024 + c);
  u16x4 o = { f2bf(v.x), f2bf(v.y), f2bf(v.z), f2bf(v.w) };
  *(u16x4*)(xbf + (size_t)r * 1024 + c) = o;
}

// u = silu(causal_conv(xin) + cb); writes f32 and bf16.  idx = r*2048+d
__global__ __launch_bounds__(256)
void conv_silu(const float* __restrict__ xz, const float* __restrict__ cw,
               const float* __restrict__ cb, float* __restrict__ u,
               u16* __restrict__ ubf) {
  const int idx = blockIdx.x * 256 + threadIdx.x;
  const int d = idx & 2047;
  const int r = idx >> 11;
  const int t = r & 1023;
  const float4 wv = *(const float4*)(cw + d * 4);
  float a = cb[d];
  if (t >= 3) {
    const float* p = xz + (size_t)(r - 3) * 4096 + d;
    a += p[0] * wv.x + p[4096] * wv.y + p[8192] * wv.z + p[12288] * wv.w;
  } else {
    const float wk[4] = { wv.x, wv.y, wv.z, wv.w };
#pragma unroll
    for (int k = 0; k < 4; ++k) {
      const int tt = t - 3 + k;
      if (tt >= 0) a += xz[(size_t)(r - 3 + k) * 4096 + d] * wk[k];
    }
  }
  const float s = a / (1.f + __expf(-a));
  u[idx] = s;
  ubf[idx] = f2bf(s);
}

// ---------------------------------------------------------------------------
// chunked selective scan: 8 chunks x 128 steps (pass1 local, pass2 global+y)
// ---------------------------------------------------------------------------
__global__ __launch_bounds__(256)
void scan_pass1(const float* __restrict__ delta, const float* __restrict__ u,
                const float* __restrict__ dbc, const float* __restrict__ A_log,
                float* __restrict__ Pb, float* __restrict__ Qb) {
  const int blk = blockIdx.x;
  const int ch = blk & 7;
  const int dt16 = (blk >> 3) & 127;
  const int b = blk >> 10;
  const int n = threadIdx.x & 15;
  const int dl = threadIdx.x >> 4;
  const int d = dt16 * 16 + dl;
  const float Ac = -expf(A_log[d * 16 + n]) * 1.44269504f;
  const int r0 = b * 1024 + ch * 128;
  float P = 1.f, h = 0.f;
  for (int j = 0; j < 128; ++j) {
    const size_t r = r0 + j;
    const float dlt = delta[r * 2048 + d];
    const float uu = u[r * 2048 + d];
    const float Bv = dbc[r * 128 + 64 + n];
    const float da = exp2f(dlt * Ac);
    P *= da;
    h = fmaf(da, h, dlt * uu * Bv);
  }
  const size_t idx = ((size_t)(b * 2048 + d) * 16 + n) * 8 + ch;
  Pb[idx] = P;
  Qb[idx] = h;
}

__global__ __launch_bounds__(256)
void scan_pass2(const float* __restrict__ delta, const float* __restrict__ u,
                const float* __restrict__ dbc, const float* __restrict__ xz,
                const float* __restrict__ A_log, const float* __restrict__ Dp,
                const float* __restrict__ Pb, const float* __restrict__ Qb,
                u16* __restrict__ ybf) {
  const int blk = blockIdx.x;
  const int ch = blk & 7;
  const int dt16 = (blk >> 3) & 127;
  const int b = blk >> 10;
  const int n = threadIdx.x & 15;
  const int dl = threadIdx.x >> 4;
  const int d = dt16 * 16 + dl;
  const float Ac = -expf(A_log[d * 16 + n]) * 1.44269504f;
  const float Dd = Dp[d];
  const int r0 = b * 1024 + ch * 128;

  float h = 0.f;
  const size_t p0 = ((size_t)(b * 2048 + d) * 16 + n) * 8;
  for (int cc = 0; cc < ch; ++cc) h = fmaf(Pb[p0 + cc], h, Qb[p0 + cc]);

  for (int j = 0; j < 128; ++j) {
    const size_t r = r0 + j;
    const float dlt = delta[r * 2048 + d];
    const float uu = u[r * 2048 + d];
    const float Bv = dbc[r * 128 + 64 + n];
    const float Cv = dbc[r * 128 + 80 + n];
    const float da = exp2f(dlt * Ac);
    h = fmaf(da, h, dlt * uu * Bv);
    float p = rowsum16(h * Cv);
    if (n == 0) {
      const float zz = xz[r * 4096 + 2048 + d];
      const float yv = (p + uu * Dd) * (zz / (1.f + __expf(-zz)));
      ybf[r * 2048 + d] = f2bf(yv);
    }
  }
}

// layernorm over 1024, writes bf16.  one wave per row; block = 4 rows.
__global__ __launch_bounds__(256)
void ln_bf(const float* __restrict__ x, const float* __restrict__ g,
           const float* __restrict__ b, u16* __restrict__ out) {
  const int r = blockIdx.x * 4 + (threadIdx.x >> 6);
  const int l = threadIdx.x & 63;
  const float4* xr = (const float4*)(x + (size_t)r * 1024);
  float4 v[4];
  float s = 0.f;
#pragma unroll
  for (int i = 0; i < 4; ++i) {
    v[i] = xr[i * 64 + l];
    s += v[i].x + v[i].y + v[i].z + v[i].w;
  }
#pragma unroll
  for (int m = 1; m < 64; m <<= 1) s += __shfl_xor(s, m, 64);
  const float mu = s * (1.f / 1024.f);
  float q = 0.f;
#pragma unroll
  for (int i = 0; i < 4; ++i) {
    float a0 = v[i].x - mu, a1 = v[i].y - mu, a2 = v[i].z - mu, a3 = v[i].w - mu;
    q += a0 * a0 + a1 * a1 + a2 * a2 + a3 * a3;
  }
#pragma unroll
  for (int m = 1; m < 64; m <<= 1) q += __shfl_xor(q, m, 64);
  const float rs = rsqrtf(q * (1.f / 1024.f) + 1e-5f);
#pragma unroll
  for (int i = 0; i < 4; ++i) {
    const int c = (i * 64 + l) * 4;
    const float4 gv = *(const float4*)(g + c);
    const float4 bv = *(const float4*)(b + c);
    u16x4 o = { f2bf((v[i].x - mu) * rs * gv.x + bv.x),
                f2bf((v[i].y - mu) * rs * gv.y + bv.y),
                f2bf((v[i].z - mu) * rs * gv.z + bv.z),
                f2bf((v[i].w - mu) * rs * gv.w + bv.w) };
    *(u16x4*)(out + (size_t)r * 1024 + c) = o;
  }
}

// ---------------------------------------------------------------------------
extern "C" void kernel_launch(void* const* d_in, const int* in_sizes, int n_in,
                              void* d_out, int out_size, void* d_ws, size_t ws_size,
                              hipStream_t stream) {
  (void)in_sizes; (void)n_in; (void)out_size; (void)ws_size;
  const int*   ids      = (const int*)d_in[0];
  const float* embed    = (const float*)d_in[1];
  const float* in_proj  = (const float*)d_in[2];
  const float* conv_w   = (const float*)d_in[3];
  const float* conv_b   = (const float*)d_in[4];
  const float* x_proj   = (const float*)d_in[5];
  const float* dt_w     = (const float*)d_in[6];
  const float* dt_b     = (const float*)d_in[7];
  const float* A_log    = (const float*)d_in[8];
  const float* Dp       = (const float*)d_in[9];
  const float* out_proj = (const float*)d_in[10];
  const float* ln_g     = (const float*)d_in[11];
  const float* ln_bta   = (const float*)d_in[12];
  const float* head     = (const float*)d_in[13];

  // f32 scratch inside d_out (all consumed before head GEMM overwrites)
  float* fout = (float*)d_out;
  float* xz   = fout;              // 2048*4096
  float* ubuf = fout + 8388608;    // 2048*2048
  float* dbuf = fout + 12582912;   // 2048*2048 (delta)
  float* dbc  = fout + 16777216;   // 2048*128
  float* xf   = fout + 17039360;   // 2048*1024
  float* Pb   = fout + 19136512;   // 524288
  float* Qb   = fout + 19660800;   // 524288

  // bf16 scratch in d_ws
  char* wp = (char*)d_ws;
  u16* headT = (u16*)wp; wp += (size_t)32000 * 1024 * 2;
  u16* WiT   = (u16*)wp; wp += (size_t)4096 * 1024 * 2;
  u16* WxT   = (u16*)wp; wp += (size_t)128 * 2048 * 2;
  u16* WdtT  = (u16*)wp; wp += (size_t)2048 * 64 * 2;
  u16* WoT   = (u16*)wp; wp += (size_t)1024 * 2048 * 2;
  u16* xbf   = (u16*)wp; wp += (size_t)2048 * 1024 * 2;
  u16* ubf   = (u16*)wp; wp += (size_t)2048 * 2048 * 2;
  u16* dtbf  = (u16*)wp; wp += (size_t)2048 * 64 * 2;
  u16* ybf   = (u16*)wp; wp += (size_t)2048 * 2048 * 2;
  u16* xlnbf = (u16*)wp; wp += (size_t)2048 * 1024 * 2;

  const dim3 tb(256);
  const dim3 tb5(512);
  embed_gather<<<2048, tb, 0, stream>>>(ids, embed, xbf);

  for (int i = 0; i < 2; ++i) {
    TBatch t{};
    int nj = 0, acc = 0;
    if (i == 0) {
      t.src[nj] = head; t.dst[nj] = headT;
      t.K[nj] = 1024; t.N[nj] = 32000; t.tx[nj] = 32;
      t.start[nj] = acc; acc += 32 * 1000; ++nj;
    }
    t.src[nj] = in_proj + (size_t)i * 1024 * 4096; t.dst[nj] = WiT;
    t.K[nj] = 1024; t.N[nj] = 4096; t.tx[nj] = 32;
    t.start[nj] = acc; acc += 32 * 128; ++nj;
    t.src[nj] = x_proj + (size_t)i * 2048 * 96; t.dst[nj] = WxT;
    t.K[nj] = 2048; t.N[nj] = 96; t.tx[nj] = 64;
    t.start[nj] = acc; acc += 64 * 4; ++nj;
    t.src[nj] = dt_w + (size_t)i * 64 * 2048; t.dst[nj] = WdtT;
    t.K[nj] = 64; t.N[nj] = 2048; t.tx[nj] = 2;
    t.start[nj] = acc; acc += 2 * 64; ++nj;
    t.src[nj] = out_proj + (size_t)i * 2048 * 1024; t.dst[nj] = WoT;
    t.K[nj] = 2048; t.N[nj] = 1024; t.tx[nj] = 64;
    t.start[nj] = acc; acc += 64 * 32; ++nj;
    t.start[nj] = acc;
    t.njobs = nj;
    transpose_batch<<<acc, tb, 0, stream>>>(t);

    gemm_bt<0><<<dim3(16, 32), tb, 0, stream>>>(xbf, WiT, xz, nullptr, nullptr, 2048, 4096, 1024);
    conv_silu<<<16384, tb, 0, stream>>>(xz, conv_w + i * 2048 * 4, conv_b + i * 2048, ubuf, ubf);
    gemm_bt<3><<<dim3(16, 1), tb, 0, stream>>>(ubf, WxT, dbc, dtbf, nullptr, 2048, 128, 2048);
    gemm_bt<1><<<dim3(16, 16), tb, 0, stream>>>(dtbf, WdtT, dbuf, nullptr, dt_b + i * 2048, 2048, 2048, 64);
    scan_pass1<<<2048, tb, 0, stream>>>(dbuf, ubuf, dbc, A_log + i * 2048 * 16, Pb, Qb);
    scan_pass2<<<2048, tb, 0, stream>>>(dbuf, ubuf, dbc, xz, A_log + i * 2048 * 16, Dp + i * 2048, Pb, Qb, ybf);
    gemm_bt<2><<<dim3(16, 8), tb, 0, stream>>>(ybf, WoT, xf, xbf, nullptr, 2048, 1024, 2048);
  }

  ln_bf<<<512, tb, 0, stream>>>(xf, ln_g, ln_bta, xlnbf);
  gemm256<0><<<dim3(8, 125), tb5, 0, stream>>>(xlnbf, headT, fout, nullptr, nullptr, 2048, 32000, 1024);
}

// Round 5
// 813.391 us; speedup vs baseline: 1.1462x; 1.0061x over previous
//
#include <hip/hip_runtime.h>

typedef unsigned short u16;
typedef __attribute__((ext_vector_type(8))) short bf16x8;
typedef __attribute__((ext_vector_type(4))) float f32x4;
typedef __attribute__((ext_vector_type(4))) u16 u16x4;

#define DEV static __device__ __forceinline__

DEV u16 f2bf(float f) {
  union { float f; unsigned u; } v; v.f = f;
  unsigned r = (v.u + 0x7fffu + ((v.u >> 16) & 1u)) >> 16;
  return (u16)r;
}

DEV void gload_lds16(const void* g, void* l) {
  __builtin_amdgcn_global_load_lds(
      (const __attribute__((address_space(1))) unsigned int*)g,
      (__attribute__((address_space(3))) unsigned int*)l, 16, 0, 0);
}

// sum over each aligned 16-lane group via DPP row rotations (pure VALU)
DEV float rowsum16(float p) {
  p += __int_as_float(__builtin_amdgcn_update_dpp(0, __float_as_int(p), 0x128, 0xF, 0xF, true)); // ror:8
  p += __int_as_float(__builtin_amdgcn_update_dpp(0, __float_as_int(p), 0x124, 0xF, 0xF, true)); // ror:4
  p += __int_as_float(__builtin_amdgcn_update_dpp(0, __float_as_int(p), 0x122, 0xF, 0xF, true)); // ror:2
  p += __int_as_float(__builtin_amdgcn_update_dpp(0, __float_as_int(p), 0x121, 0xF, 0xF, true)); // ror:1
  return p;
}

// ---------------------------------------------------------------------------
// 256x256 8-wave MFMA GEMM — m201 8-phase template port (HEAD GEMM only).
// Iter = 2 K-tiles (BK=64 each). Phase = {ds_read subtile; stage 1 half-tile;
// barrier; lgkmcnt(0); setprio; 16 MFMA; setprio; barrier}. vmcnt(4) at
// phases 4 & 8 only (ledger: forces the tiles read next phase, leaves 2
// half-tiles in flight). Stage slots race-checked against barrier-confirmed
// last reads. LDS 2buf x (A[256][64]+B[256][64]) = 128 KiB, XOR-swizzled
// (chunk ^= row&7; linear gload_lds dest, inverse-swizzled global source).
// Requires K % 128 == 0, K >= 128, M % 256 == 0, N % 256 == 0.
// ---------------------------------------------------------------------------
#define STGH(buf, mat, half, P, kt) { \
    const int r_ = (half) * 128 + sr0; \
    gload_lds16((P) + (size_t)r_ * K + (kt) + scs, &lds[buf][mat][r_][sc8]); \
    gload_lds16((P) + (size_t)(r_ + 64) * K + (kt) + scs, &lds[buf][mat][r_ + 64][sc8]); }
#define LDB(buf) _Pragma("unroll") for (int n = 0; n < 4; ++n) { \
    const int row = wn * 64 + n * 16 + lr; \
    _Pragma("unroll") for (int kk = 0; kk < 2; ++kk) \
      bfr[n][kk] = *(const bf16x8*)&lds[buf][1][row][(((kk << 2) | lq) ^ (row & 7)) << 3]; }
#define LDA(buf, p) _Pragma("unroll") for (int mi = 0; mi < 2; ++mi) { \
    const int row = wm * 128 + ((p) * 2 + mi) * 16 + lr; \
    _Pragma("unroll") for (int kk = 0; kk < 2; ++kk) \
      af[mi][kk] = *(const bf16x8*)&lds[buf][0][row][(((kk << 2) | lq) ^ (row & 7)) << 3]; }
#define MM(p) __builtin_amdgcn_s_setprio(1); \
  _Pragma("unroll") for (int kk = 0; kk < 2; ++kk) \
  _Pragma("unroll") for (int mi = 0; mi < 2; ++mi) \
  _Pragma("unroll") for (int n = 0; n < 4; ++n) \
    acc[(p) * 2 + mi][n] = __builtin_amdgcn_mfma_f32_16x16x32_bf16(af[mi][kk], bfr[n][kk], acc[(p) * 2 + mi][n], 0, 0, 0); \
  __builtin_amdgcn_s_setprio(0);
#define BAR() { __builtin_amdgcn_s_barrier(); asm volatile("" ::: "memory"); }
#define WLG() { asm volatile("s_waitcnt lgkmcnt(0)" ::: "memory"); __builtin_amdgcn_sched_barrier(0); }
#define VMC(n) asm volatile("s_waitcnt vmcnt(" #n ")" ::: "memory")

template<int EPI>
__global__ __launch_bounds__(512, 1)
void gemm256(const u16* __restrict__ A, const u16* __restrict__ BT,
             float* __restrict__ C, u16* __restrict__ Cbf,
             const float* __restrict__ bias, int M, int N, int K) {
  __shared__ u16 lds[2][2][256][64];   // [buf][A=0,B=1][row][k]
  const int t = threadIdx.x;
  const int l = t & 63;
  const int w = t >> 6;
  const int wm = w >> 2;        // 0..1
  const int wn = w & 3;         // 0..3
  const int lr = l & 15, lq = l >> 4;

  // bijective XCD-chunked swizzle; gridDim.x == 8 (M-tiles), nwg % 8 == 0
  const int gn = N >> 8;
  const int nwg = gn << 3;
  const int orig = blockIdx.y * 8 + blockIdx.x;
  const int q = nwg >> 3;
  const int swz = (orig & 7) * q + (orig >> 3);
  const int bx = swz & 7;
  const int by = swz >> 3;

  const u16* Ap = A + (size_t)bx * 256 * K;
  const u16* Bp = BT + (size_t)by * 256 * K;
  const int sr0 = t >> 3;                 // 0..63
  const int sc8 = (t & 7) << 3;           // linear LDS chunk col (u16)
  const int scs = (((t & 7) ^ (sr0 & 7)) << 3);  // inverse-swizzled src col

  f32x4 acc[8][4];
#pragma unroll
  for (int m = 0; m < 8; ++m)
#pragma unroll
    for (int n = 0; n < 4; ++n) acc[m][n] = (f32x4){0.f, 0.f, 0.f, 0.f};

  const int NI = K >> 7;   // iters of 2 K-tiles
  // ---- prologue: B(0), A(0), B(1); force B(0),A(0); leave B(1) in flight
  STGH(0, 1, 0, Bp, 0) STGH(0, 1, 1, Bp, 0)
  STGH(0, 0, 0, Ap, 0) STGH(0, 0, 1, Ap, 0)
  STGH(1, 1, 0, Bp, 64) STGH(1, 1, 1, Bp, 64)
  VMC(4);
  BAR();

  for (int ip = 0; ip < NI; ++ip) {
    const int k0 = ip << 7;
    const bool m2 = (k0 + 128) < K;
    const bool m3 = (k0 + 192) < K;
    bf16x8 bfr[4][2], af[2][2];
    // ============ tile t0 (buf0) ============
    // ph1: B frags + A mpair0; stage A(t1).h0
    LDB(0) LDA(0, 0)
    STGH(1, 0, 0, Ap, k0 + 64)
    BAR(); WLG(); MM(0) BAR();
    // ph2: A mpair1; stage A(t1).h1
    LDA(0, 1)
    STGH(1, 0, 1, Ap, k0 + 64)
    BAR(); WLG(); MM(1) BAR();
    // ph3: A mpair2; stage B(t0+2).h0
    LDA(0, 2)
    if (m2) STGH(0, 1, 0, Bp, k0 + 128)
    BAR(); WLG(); MM(2) BAR();
    // ph4: A mpair3; stage B(t0+2).h1; vmcnt forces B(t1)+A(t1)
    LDA(0, 3)
    if (m2) STGH(0, 1, 1, Bp, k0 + 128)
    BAR(); WLG(); MM(3)
    if (m2) { VMC(4); } else { VMC(0); }
    BAR();
    // ============ tile t1 (buf1) ============
    // ph5: B frags + A mpair0; stage A(t0+2).h0
    LDB(1) LDA(1, 0)
    if (m2) STGH(0, 0, 0, Ap, k0 + 128)
    BAR(); WLG(); MM(0) BAR();
    // ph6: A mpair1; stage A(t0+2).h1
    LDA(1, 1)
    if (m2) STGH(0, 0, 1, Ap, k0 + 128)
    BAR(); WLG(); MM(1) BAR();
    // ph7: A mpair2; stage B(t1+2).h0
    LDA(1, 2)
    if (m3) STGH(1, 1, 0, Bp, k0 + 192)
    BAR(); WLG(); MM(2) BAR();
    // ph8: A mpair3; stage B(t1+2).h1; vmcnt forces B(t0+2)+A(t0+2)
    LDA(1, 3)
    if (m3) STGH(1, 1, 1, Bp, k0 + 192)
    BAR(); WLG(); MM(3)
    if (m3) { VMC(4); } else { VMC(0); }
    BAR();
  }

  const int lg4 = lq * 4;
#pragma unroll
  for (int m = 0; m < 8; ++m) {
    const int grow0 = bx * 256 + wm * 128 + m * 16 + lg4;
#pragma unroll
    for (int n = 0; n < 4; ++n) {
      const int gcol = by * 256 + wn * 64 + n * 16 + lr;
      float bv = 0.f;
      if (EPI == 1) bv = bias[gcol];
#pragma unroll
      for (int r = 0; r < 4; ++r) {
        float v = acc[m][n][r];
        if (EPI == 1) {
          v += bv;
          v = fmaxf(v, 0.f) + log1pf(expf(-fabsf(v)));
        }
        const size_t idx = (size_t)(grow0 + r) * N + gcol;
        C[idx] = v;
        if (EPI == 2) Cbf[idx] = f2bf(v);
      }
    }
  }
}
#undef STGH
#undef LDB
#undef LDA
#undef MM
#undef BAR
#undef WLG
#undef VMC

// ---------------------------------------------------------------------------
// 128x128 BK=64 GEMM for the small-N GEMMs (fills the GPU with blocks).
// EPI: 0 = f32; 1 = +bias, softplus, f32; 2 = f32 + bf16; 3 = f32 + bf16 of
//      cols<64 into Cbf with row stride 64 (fused dt extract).
// gridDim.x MUST be 16; nwg % 8 == 0.
// ---------------------------------------------------------------------------
template<int EPI>
__global__ __launch_bounds__(256)
void gemm_bt(const u16* __restrict__ A, const u16* __restrict__ BT,
             float* __restrict__ C, u16* __restrict__ Cbf,
             const float* __restrict__ bias, int M, int N, int K) {
  __shared__ u16 As[128][64];
  __shared__ u16 Bs[128][64];
  const int t = threadIdx.x;
  const int l = t & 63;
  const int w = t >> 6;
  const int wr = (w >> 1) * 64;
  const int wc = (w & 1) * 64;

  const int nwg = gridDim.x * gridDim.y;
  const int orig = blockIdx.y * gridDim.x + blockIdx.x;
  const int swz = (orig & 7) * (nwg >> 3) + (orig >> 3);
  const int bx = swz & 15;
  const int by = swz >> 4;

  const size_t aoff = (size_t)bx * 128 * K;
  const size_t boff = (size_t)by * 128 * K;
  const int r0 = t >> 3;
  const int c0s = (((t & 7) ^ (r0 & 7)) << 3);
  const int c0l = (t & 7) << 3;
  const int lr = l & 15;
  const int lq = l >> 4;

  f32x4 acc[4][4];
#pragma unroll
  for (int i = 0; i < 4; ++i)
#pragma unroll
    for (int j = 0; j < 4; ++j) acc[i][j] = (f32x4){0.f, 0.f, 0.f, 0.f};

  for (int kt = 0; kt < K; kt += 64) {
    __syncthreads();
#pragma unroll
    for (int i = 0; i < 4; ++i) {
      const int r = r0 + i * 32;
      gload_lds16(A + aoff + (size_t)r * K + kt + c0s, &As[r][c0l]);
      gload_lds16(BT + boff + (size_t)r * K + kt + c0s, &Bs[r][c0l]);
    }
    __syncthreads();
#pragma unroll
    for (int kk = 0; kk < 2; ++kk) {
      bf16x8 af[4], bfr[4];
#pragma unroll
      for (int i = 0; i < 4; ++i) {
        const int row = wr + i * 16 + lr;
        af[i] = *(const bf16x8*)&As[row][(((kk << 2) | lq) ^ (row & 7)) << 3];
      }
#pragma unroll
      for (int j = 0; j < 4; ++j) {
        const int row = wc + j * 16 + lr;
        bfr[j] = *(const bf16x8*)&Bs[row][(((kk << 2) | lq) ^ (row & 7)) << 3];
      }
#pragma unroll
      for (int i = 0; i < 4; ++i)
#pragma unroll
        for (int j = 0; j < 4; ++j)
          acc[i][j] = __builtin_amdgcn_mfma_f32_16x16x32_bf16(af[i], bfr[j], acc[i][j], 0, 0, 0);
    }
  }

  const int lg4 = lq * 4;
#pragma unroll
  for (int i = 0; i < 4; ++i) {
    const int grow0 = bx * 128 + wr + i * 16 + lg4;
#pragma unroll
    for (int j = 0; j < 4; ++j) {
      const int gcol = by * 128 + wc + j * 16 + lr;
      float bv = 0.f;
      if (EPI == 1) bv = bias[gcol];
#pragma unroll
      for (int r = 0; r < 4; ++r) {
        float v = acc[i][j][r];
        if (EPI == 1) {
          v += bv;
          v = fmaxf(v, 0.f) + log1pf(expf(-fabsf(v)));   // stable softplus
        }
        const size_t idx = (size_t)(grow0 + r) * N + gcol;
        C[idx] = v;
        if (EPI == 2) Cbf[idx] = f2bf(v);
        if (EPI == 3 && gcol < 64) Cbf[(size_t)(grow0 + r) * 64 + gcol] = f2bf(v);
      }
    }
  }
}

// ---------------------------------------------------------------------------
// batched transpose+convert: f32 (K,N) -> bf16 (Npad,K), zero-pad n>=N.
// ---------------------------------------------------------------------------
struct TBatch {
  const float* src[5];
  u16* dst[5];
  int K[5], N[5], tx[5];
  int start[6];
  int njobs;
};

__global__ __launch_bounds__(256)
void transpose_batch(TBatch tb) {
  const int tile = blockIdx.x;
  int j = 0;
  while (j + 1 < tb.njobs && tile >= tb.start[j + 1]) ++j;
  const int lt = tile - tb.start[j];
  const int K = tb.K[j];
  const int N = tb.N[j];
  const int kb = (lt % tb.tx[j]) * 32;
  const int nb = (lt / tb.tx[j]) * 32;
  const float* __restrict__ in = tb.src[j];
  u16* __restrict__ out = tb.dst[j];

  __shared__ float tile_s[32][33];
  const int tx = threadIdx.x & 31;
  const int ty = threadIdx.x >> 5;
#pragma unroll
  for (int s = 0; s < 4; ++s) {
    const int k = kb + ty + s * 8;
    const int n = nb + tx;
    tile_s[ty + s * 8][tx] = (n < N) ? in[(size_t)k * N + n] : 0.f;
  }
  __syncthreads();
#pragma unroll
  for (int s = 0; s < 4; ++s) {
    const int n = nb + ty + s * 8;
    const int k = kb + tx;
    out[(size_t)n * K + k] = f2bf(tile_s[tx][ty + s * 8]);
  }
}

__global__ __launch_bounds__(256)
void embed_gather(const int* __restrict__ ids, const float* __restrict__ embed,
                  u16* __restrict__ xbf) {
  const int r = blockIdx.x;
  const int c = threadIdx.x * 4;
  const int id = ids[r];
  const float4 v = *(const float4*)(embed + (size_t)id * 1024 + c);
  u16x4 o = { f2bf(v.x), f2bf(v.y), f2bf(v.z), f2bf(v.w) };
  *(u16x4*)(xbf + (size_t)r * 1024 + c) = o;
}

// u = silu(causal_conv(xin) + cb); writes f32 and bf16.  idx = r*2048+d
__global__ __launch_bounds__(256)
void conv_silu(const float* __restrict__ xz, const float* __restrict__ cw,
               const float* __restrict__ cb, float* __restrict__ u,
               u16* __restrict__ ubf) {
  const int idx = blockIdx.x * 256 + threadIdx.x;
  const int d = idx & 2047;
  const int r = idx >> 11;
  const int t = r & 1023;
  const float4 wv = *(const float4*)(cw + d * 4);
  float a = cb[d];
  if (t >= 3) {
    const float* p = xz + (size_t)(r - 3) * 4096 + d;
    a += p[0] * wv.x + p[4096] * wv.y + p[8192] * wv.z + p[12288] * wv.w;
  } else {
    const float wk[4] = { wv.x, wv.y, wv.z, wv.w };
#pragma unroll
    for (int k = 0; k < 4; ++k) {
      const int tt = t - 3 + k;
      if (tt >= 0) a += xz[(size_t)(r - 3 + k) * 4096 + d] * wk[k];
    }
  }
  const float s = a / (1.f + __expf(-a));
  u[idx] = s;
  ubf[idx] = f2bf(s);
}

// ---------------------------------------------------------------------------
// chunked selective scan: 8 chunks x 128 steps (pass1 local, pass2 global+y)
// ---------------------------------------------------------------------------
__global__ __launch_bounds__(256)
void scan_pass1(const float* __restrict__ delta, const float* __restrict__ u,
                const float* __restrict__ dbc, const float* __restrict__ A_log,
                float* __restrict__ Pb, float* __restrict__ Qb) {
  const int blk = blockIdx.x;
  const int ch = blk & 7;
  const int dt16 = (blk >> 3) & 127;
  const int b = blk >> 10;
  const int n = threadIdx.x & 15;
  const int dl = threadIdx.x >> 4;
  const int d = dt16 * 16 + dl;
  const float Ac = -expf(A_log[d * 16 + n]) * 1.44269504f;
  const int r0 = b * 1024 + ch * 128;
  float P = 1.f, h = 0.f;
  for (int j = 0; j < 128; ++j) {
    const size_t r = r0 + j;
    const float dlt = delta[r * 2048 + d];
    const float uu = u[r * 2048 + d];
    const float Bv = dbc[r * 128 + 64 + n];
    const float da = exp2f(dlt * Ac);
    P *= da;
    h = fmaf(da, h, dlt * uu * Bv);
  }
  const size_t idx = ((size_t)(b * 2048 + d) * 16 + n) * 8 + ch;
  Pb[idx] = P;
  Qb[idx] = h;
}

__global__ __launch_bounds__(256)
void scan_pass2(const float* __restrict__ delta, const float* __restrict__ u,
                const float* __restrict__ dbc, const float* __restrict__ xz,
                const float* __restrict__ A_log, const float* __restrict__ Dp,
                const float* __restrict__ Pb, const float* __restrict__ Qb,
                u16* __restrict__ ybf) {
  const int blk = blockIdx.x;
  const int ch = blk & 7;
  const int dt16 = (blk >> 3) & 127;
  const int b = blk >> 10;
  const int n = threadIdx.x & 15;
  const int dl = threadIdx.x >> 4;
  const int d = dt16 * 16 + dl;
  const float Ac = -expf(A_log[d * 16 + n]) * 1.44269504f;
  const float Dd = Dp[d];
  const int r0 = b * 1024 + ch * 128;

  float h = 0.f;
  const size_t p0 = ((size_t)(b * 2048 + d) * 16 + n) * 8;
  for (int cc = 0; cc < ch; ++cc) h = fmaf(Pb[p0 + cc], h, Qb[p0 + cc]);

  for (int j = 0; j < 128; ++j) {
    const size_t r = r0 + j;
    const float dlt = delta[r * 2048 + d];
    const float uu = u[r * 2048 + d];
    const float Bv = dbc[r * 128 + 64 + n];
    const float Cv = dbc[r * 128 + 80 + n];
    const float da = exp2f(dlt * Ac);
    h = fmaf(da, h, dlt * uu * Bv);
    float p = rowsum16(h * Cv);
    if (n == 0) {
      const float zz = xz[r * 4096 + 2048 + d];
      const float yv = (p + uu * Dd) * (zz / (1.f + __expf(-zz)));
      ybf[r * 2048 + d] = f2bf(yv);
    }
  }
}

// layernorm over 1024, writes bf16.  one wave per row; block = 4 rows.
__global__ __launch_bounds__(256)
void ln_bf(const float* __restrict__ x, const float* __restrict__ g,
           const float* __restrict__ b, u16* __restrict__ out) {
  const int r = blockIdx.x * 4 + (threadIdx.x >> 6);
  const int l = threadIdx.x & 63;
  const float4* xr = (const float4*)(x + (size_t)r * 1024);
  float4 v[4];
  float s = 0.f;
#pragma unroll
  for (int i = 0; i < 4; ++i) {
    v[i] = xr[i * 64 + l];
    s += v[i].x + v[i].y + v[i].z + v[i].w;
  }
#pragma unroll
  for (int m = 1; m < 64; m <<= 1) s += __shfl_xor(s, m, 64);
  const float mu = s * (1.f / 1024.f);
  float q = 0.f;
#pragma unroll
  for (int i = 0; i < 4; ++i) {
    float a0 = v[i].x - mu, a1 = v[i].y - mu, a2 = v[i].z - mu, a3 = v[i].w - mu;
    q += a0 * a0 + a1 * a1 + a2 * a2 + a3 * a3;
  }
#pragma unroll
  for (int m = 1; m < 64; m <<= 1) q += __shfl_xor(q, m, 64);
  const float rs = rsqrtf(q * (1.f / 1024.f) + 1e-5f);
#pragma unroll
  for (int i = 0; i < 4; ++i) {
    const int c = (i * 64 + l) * 4;
    const float4 gv = *(const float4*)(g + c);
    const float4 bv = *(const float4*)(b + c);
    u16x4 o = { f2bf((v[i].x - mu) * rs * gv.x + bv.x),
                f2bf((v[i].y - mu) * rs * gv.y + bv.y),
                f2bf((v[i].z - mu) * rs * gv.z + bv.z),
                f2bf((v[i].w - mu) * rs * gv.w + bv.w) };
    *(u16x4*)(out + (size_t)r * 1024 + c) = o;
  }
}

// ---------------------------------------------------------------------------
extern "C" void kernel_launch(void* const* d_in, const int* in_sizes, int n_in,
                              void* d_out, int out_size, void* d_ws, size_t ws_size,
                              hipStream_t stream) {
  (void)in_sizes; (void)n_in; (void)out_size; (void)ws_size;
  const int*   ids      = (const int*)d_in[0];
  const float* embed    = (const float*)d_in[1];
  const float* in_proj  = (const float*)d_in[2];
  const float* conv_w   = (const float*)d_in[3];
  const float* conv_b   = (const float*)d_in[4];
  const float* x_proj   = (const float*)d_in[5];
  const float* dt_w     = (const float*)d_in[6];
  const float* dt_b     = (const float*)d_in[7];
  const float* A_log    = (const float*)d_in[8];
  const float* Dp       = (const float*)d_in[9];
  const float* out_proj = (const float*)d_in[10];
  const float* ln_g     = (const float*)d_in[11];
  const float* ln_bta   = (const float*)d_in[12];
  const float* head     = (const float*)d_in[13];

  // f32 scratch inside d_out (all consumed before head GEMM overwrites)
  float* fout = (float*)d_out;
  float* xz   = fout;              // 2048*4096
  float* ubuf = fout + 8388608;    // 2048*2048
  float* dbuf = fout + 12582912;   // 2048*2048 (delta)
  float* dbc  = fout + 16777216;   // 2048*128
  float* xf   = fout + 17039360;   // 2048*1024
  float* Pb   = fout + 19136512;   // 524288
  float* Qb   = fout + 19660800;   // 524288

  // bf16 scratch in d_ws
  char* wp = (char*)d_ws;
  u16* headT = (u16*)wp; wp += (size_t)32000 * 1024 * 2;
  u16* WiT   = (u16*)wp; wp += (size_t)4096 * 1024 * 2;
  u16* WxT   = (u16*)wp; wp += (size_t)128 * 2048 * 2;
  u16* WdtT  = (u16*)wp; wp += (size_t)2048 * 64 * 2;
  u16* WoT   = (u16*)wp; wp += (size_t)1024 * 2048 * 2;
  u16* xbf   = (u16*)wp; wp += (size_t)2048 * 1024 * 2;
  u16* ubf   = (u16*)wp; wp += (size_t)2048 * 2048 * 2;
  u16* dtbf  = (u16*)wp; wp += (size_t)2048 * 64 * 2;
  u16* ybf   = (u16*)wp; wp += (size_t)2048 * 2048 * 2;
  u16* xlnbf = (u16*)wp; wp += (size_t)2048 * 1024 * 2;

  const dim3 tb(256);
  const dim3 tb5(512);
  embed_gather<<<2048, tb, 0, stream>>>(ids, embed, xbf);

  for (int i = 0; i < 2; ++i) {
    TBatch t{};
    int nj = 0, acc = 0;
    if (i == 0) {
      t.src[nj] = head; t.dst[nj] = headT;
      t.K[nj] = 1024; t.N[nj] = 32000; t.tx[nj] = 32;
      t.start[nj] = acc; acc += 32 * 1000; ++nj;
    }
    t.src[nj] = in_proj + (size_t)i * 1024 * 4096; t.dst[nj] = WiT;
    t.K[nj] = 1024; t.N[nj] = 4096; t.tx[nj] = 32;
    t.start[nj] = acc; acc += 32 * 128; ++nj;
    t.src[nj] = x_proj + (size_t)i * 2048 * 96; t.dst[nj] = WxT;
    t.K[nj] = 2048; t.N[nj] = 96; t.tx[nj] = 64;
    t.start[nj] = acc; acc += 64 * 4; ++nj;
    t.src[nj] = dt_w + (size_t)i * 64 * 2048; t.dst[nj] = WdtT;
    t.K[nj] = 64; t.N[nj] = 2048; t.tx[nj] = 2;
    t.start[nj] = acc; acc += 2 * 64; ++nj;
    t.src[nj] = out_proj + (size_t)i * 2048 * 1024; t.dst[nj] = WoT;
    t.K[nj] = 2048; t.N[nj] = 1024; t.tx[nj] = 64;
    t.start[nj] = acc; acc += 64 * 32; ++nj;
    t.start[nj] = acc;
    t.njobs = nj;
    transpose_batch<<<acc, tb, 0, stream>>>(t);

    gemm_bt<0><<<dim3(16, 32), tb, 0, stream>>>(xbf, WiT, xz, nullptr, nullptr, 2048, 4096, 1024);
    conv_silu<<<16384, tb, 0, stream>>>(xz, conv_w + i * 2048 * 4, conv_b + i * 2048, ubuf, ubf);
    gemm_bt<3><<<dim3(16, 1), tb, 0, stream>>>(ubf, WxT, dbc, dtbf, nullptr, 2048, 128, 2048);
    gemm_bt<1><<<dim3(16, 16), tb, 0, stream>>>(dtbf, WdtT, dbuf, nullptr, dt_b + i * 2048, 2048, 2048, 64);
    scan_pass1<<<2048, tb, 0, stream>>>(dbuf, ubuf, dbc, A_log + i * 2048 * 16, Pb, Qb);
    scan_pass2<<<2048, tb, 0, stream>>>(dbuf, ubuf, dbc, xz, A_log + i * 2048 * 16, Dp + i * 2048, Pb, Qb, ybf);
    gemm_bt<2><<<dim3(16, 8), tb, 0, stream>>>(ybf, WoT, xf, xbf, nullptr, 2048, 1024, 2048);
  }

  ln_bf<<<512, tb, 0, stream>>>(xf, ln_g, ln_bta, xlnbf);
  gemm256<0><<<dim3(8, 125), tb5, 0, stream>>>(xlnbf, headT, fout, nullptr, nullptr, 2048, 32000, 1024);
}

// Round 6
// 739.889 us; speedup vs baseline: 1.2601x; 1.0993x over previous
//
#include <hip/hip_runtime.h>

typedef unsigned short u16;
typedef __attribute__((ext_vector_type(8))) short bf16x8;
typedef __attribute__((ext_vector_type(4))) float f32x4;
typedef __attribute__((ext_vector_type(4))) u16 u16x4;

#define DEV static __device__ __forceinline__

DEV u16 f2bf(float f) {
  union { float f; unsigned u; } v; v.f = f;
  unsigned r = (v.u + 0x7fffu + ((v.u >> 16) & 1u)) >> 16;
  return (u16)r;
}

DEV void gload_lds16(const void* g, void* l) {
  __builtin_amdgcn_global_load_lds(
      (const __attribute__((address_space(1))) unsigned int*)g,
      (__attribute__((address_space(3))) unsigned int*)l, 16, 0, 0);
}

// sum over each aligned 16-lane group via DPP row rotations (pure VALU)
DEV float rowsum16(float p) {
  p += __int_as_float(__builtin_amdgcn_update_dpp(0, __float_as_int(p), 0x128, 0xF, 0xF, true)); // ror:8
  p += __int_as_float(__builtin_amdgcn_update_dpp(0, __float_as_int(p), 0x124, 0xF, 0xF, true)); // ror:4
  p += __int_as_float(__builtin_amdgcn_update_dpp(0, __float_as_int(p), 0x122, 0xF, 0xF, true)); // ror:2
  p += __int_as_float(__builtin_amdgcn_update_dpp(0, __float_as_int(p), 0x121, 0xF, 0xF, true)); // ror:1
  return p;
}

// ---------------------------------------------------------------------------
// 256x256 8-wave MFMA GEMM — m201 8-phase (HEAD GEMM only). Unchanged r5.
// ---------------------------------------------------------------------------
#define STGH(buf, mat, half, P, kt) { \
    const int r_ = (half) * 128 + sr0; \
    gload_lds16((P) + (size_t)r_ * K + (kt) + scs, &lds[buf][mat][r_][sc8]); \
    gload_lds16((P) + (size_t)(r_ + 64) * K + (kt) + scs, &lds[buf][mat][r_ + 64][sc8]); }
#define LDB(buf) _Pragma("unroll") for (int n = 0; n < 4; ++n) { \
    const int row = wn * 64 + n * 16 + lr; \
    _Pragma("unroll") for (int kk = 0; kk < 2; ++kk) \
      bfr[n][kk] = *(const bf16x8*)&lds[buf][1][row][(((kk << 2) | lq) ^ (row & 7)) << 3]; }
#define LDA(buf, p) _Pragma("unroll") for (int mi = 0; mi < 2; ++mi) { \
    const int row = wm * 128 + ((p) * 2 + mi) * 16 + lr; \
    _Pragma("unroll") for (int kk = 0; kk < 2; ++kk) \
      af[mi][kk] = *(const bf16x8*)&lds[buf][0][row][(((kk << 2) | lq) ^ (row & 7)) << 3]; }
#define MM(p) __builtin_amdgcn_s_setprio(1); \
  _Pragma("unroll") for (int kk = 0; kk < 2; ++kk) \
  _Pragma("unroll") for (int mi = 0; mi < 2; ++mi) \
  _Pragma("unroll") for (int n = 0; n < 4; ++n) \
    acc[(p) * 2 + mi][n] = __builtin_amdgcn_mfma_f32_16x16x32_bf16(af[mi][kk], bfr[n][kk], acc[(p) * 2 + mi][n], 0, 0, 0); \
  __builtin_amdgcn_s_setprio(0);
#define BAR() { __builtin_amdgcn_s_barrier(); asm volatile("" ::: "memory"); }
#define WLG() { asm volatile("s_waitcnt lgkmcnt(0)" ::: "memory"); __builtin_amdgcn_sched_barrier(0); }
#define VMC(n) asm volatile("s_waitcnt vmcnt(" #n ")" ::: "memory")

template<int EPI>
__global__ __launch_bounds__(512, 1)
void gemm256(const u16* __restrict__ A, const u16* __restrict__ BT,
             float* __restrict__ C, u16* __restrict__ Cbf,
             const float* __restrict__ bias, int M, int N, int K) {
  __shared__ u16 lds[2][2][256][64];   // [buf][A=0,B=1][row][k]
  const int t = threadIdx.x;
  const int l = t & 63;
  const int w = t >> 6;
  const int wm = w >> 2;        // 0..1
  const int wn = w & 3;         // 0..3
  const int lr = l & 15, lq = l >> 4;

  const int gn = N >> 8;
  const int nwg = gn << 3;
  const int orig = blockIdx.y * 8 + blockIdx.x;
  const int q = nwg >> 3;
  const int swz = (orig & 7) * q + (orig >> 3);
  const int bx = swz & 7;
  const int by = swz >> 3;

  const u16* Ap = A + (size_t)bx * 256 * K;
  const u16* Bp = BT + (size_t)by * 256 * K;
  const int sr0 = t >> 3;
  const int sc8 = (t & 7) << 3;
  const int scs = (((t & 7) ^ (sr0 & 7)) << 3);

  f32x4 acc[8][4];
#pragma unroll
  for (int m = 0; m < 8; ++m)
#pragma unroll
    for (int n = 0; n < 4; ++n) acc[m][n] = (f32x4){0.f, 0.f, 0.f, 0.f};

  const int NI = K >> 7;
  STGH(0, 1, 0, Bp, 0) STGH(0, 1, 1, Bp, 0)
  STGH(0, 0, 0, Ap, 0) STGH(0, 0, 1, Ap, 0)
  STGH(1, 1, 0, Bp, 64) STGH(1, 1, 1, Bp, 64)
  VMC(4);
  BAR();

  for (int ip = 0; ip < NI; ++ip) {
    const int k0 = ip << 7;
    const bool m2 = (k0 + 128) < K;
    const bool m3 = (k0 + 192) < K;
    bf16x8 bfr[4][2], af[2][2];
    LDB(0) LDA(0, 0)
    STGH(1, 0, 0, Ap, k0 + 64)
    BAR(); WLG(); MM(0) BAR();
    LDA(0, 1)
    STGH(1, 0, 1, Ap, k0 + 64)
    BAR(); WLG(); MM(1) BAR();
    LDA(0, 2)
    if (m2) STGH(0, 1, 0, Bp, k0 + 128)
    BAR(); WLG(); MM(2) BAR();
    LDA(0, 3)
    if (m2) STGH(0, 1, 1, Bp, k0 + 128)
    BAR(); WLG(); MM(3)
    if (m2) { VMC(4); } else { VMC(0); }
    BAR();
    LDB(1) LDA(1, 0)
    if (m2) STGH(0, 0, 0, Ap, k0 + 128)
    BAR(); WLG(); MM(0) BAR();
    LDA(1, 1)
    if (m2) STGH(0, 0, 1, Ap, k0 + 128)
    BAR(); WLG(); MM(1) BAR();
    LDA(1, 2)
    if (m3) STGH(1, 1, 0, Bp, k0 + 192)
    BAR(); WLG(); MM(2) BAR();
    LDA(1, 3)
    if (m3) STGH(1, 1, 1, Bp, k0 + 192)
    BAR(); WLG(); MM(3)
    if (m3) { VMC(4); } else { VMC(0); }
    BAR();
  }

  const int lg4 = lq * 4;
#pragma unroll
  for (int m = 0; m < 8; ++m) {
    const int grow0 = bx * 256 + wm * 128 + m * 16 + lg4;
#pragma unroll
    for (int n = 0; n < 4; ++n) {
      const int gcol = by * 256 + wn * 64 + n * 16 + lr;
#pragma unroll
      for (int r = 0; r < 4; ++r) {
        const size_t idx = (size_t)(grow0 + r) * N + gcol;
        C[idx] = acc[m][n][r];
      }
    }
  }
}
#undef STGH
#undef LDB
#undef LDA
#undef MM
#undef BAR
#undef WLG
#undef VMC

// ---------------------------------------------------------------------------
// 128x128 BK=64 GEMM.  EPI: 0 = f32; 1 = +bias, softplus, f32.
// gridDim.x MUST be 16; nwg % 8 == 0.
// ---------------------------------------------------------------------------
template<int EPI>
__global__ __launch_bounds__(256)
void gemm_bt(const u16* __restrict__ A, const u16* __restrict__ BT,
             float* __restrict__ C, u16* __restrict__ Cbf,
             const float* __restrict__ bias, int M, int N, int K) {
  __shared__ u16 As[128][64];
  __shared__ u16 Bs[128][64];
  const int t = threadIdx.x;
  const int l = t & 63;
  const int w = t >> 6;
  const int wr = (w >> 1) * 64;
  const int wc = (w & 1) * 64;

  const int nwg = gridDim.x * gridDim.y;
  const int orig = blockIdx.y * gridDim.x + blockIdx.x;
  const int swz = (orig & 7) * (nwg >> 3) + (orig >> 3);
  const int bx = swz & 15;
  const int by = swz >> 4;

  const size_t aoff = (size_t)bx * 128 * K;
  const size_t boff = (size_t)by * 128 * K;
  const int r0 = t >> 3;
  const int c0s = (((t & 7) ^ (r0 & 7)) << 3);
  const int c0l = (t & 7) << 3;
  const int lr = l & 15;
  const int lq = l >> 4;

  f32x4 acc[4][4];
#pragma unroll
  for (int i = 0; i < 4; ++i)
#pragma unroll
    for (int j = 0; j < 4; ++j) acc[i][j] = (f32x4){0.f, 0.f, 0.f, 0.f};

  for (int kt = 0; kt < K; kt += 64) {
    __syncthreads();
#pragma unroll
    for (int i = 0; i < 4; ++i) {
      const int r = r0 + i * 32;
      gload_lds16(A + aoff + (size_t)r * K + kt + c0s, &As[r][c0l]);
      gload_lds16(BT + boff + (size_t)r * K + kt + c0s, &Bs[r][c0l]);
    }
    __syncthreads();
#pragma unroll
    for (int kk = 0; kk < 2; ++kk) {
      bf16x8 af[4], bfr[4];
#pragma unroll
      for (int i = 0; i < 4; ++i) {
        const int row = wr + i * 16 + lr;
        af[i] = *(const bf16x8*)&As[row][(((kk << 2) | lq) ^ (row & 7)) << 3];
      }
#pragma unroll
      for (int j = 0; j < 4; ++j) {
        const int row = wc + j * 16 + lr;
        bfr[j] = *(const bf16x8*)&Bs[row][(((kk << 2) | lq) ^ (row & 7)) << 3];
      }
#pragma unroll
      for (int i = 0; i < 4; ++i)
#pragma unroll
        for (int j = 0; j < 4; ++j)
          acc[i][j] = __builtin_amdgcn_mfma_f32_16x16x32_bf16(af[i], bfr[j], acc[i][j], 0, 0, 0);
    }
  }

  const int lg4 = lq * 4;
#pragma unroll
  for (int i = 0; i < 4; ++i) {
    const int grow0 = bx * 128 + wr + i * 16 + lg4;
#pragma unroll
    for (int j = 0; j < 4; ++j) {
      const int gcol = by * 128 + wc + j * 16 + lr;
      float bv = 0.f;
      if (EPI == 1) bv = bias[gcol];
#pragma unroll
      for (int r = 0; r < 4; ++r) {
        float v = acc[i][j][r];
        if (EPI == 1) {
          v += bv;
          v = fmaxf(v, 0.f) + log1pf(expf(-fabsf(v)));   // stable softplus
        }
        C[(size_t)(grow0 + r) * N + gcol] = v;
      }
    }
  }
}

// ---------------------------------------------------------------------------
// x_proj split-K: A=ubf[2048,2048], BT=WxT[128,2048] (both ld 2048).
// grid (16, 8): bx = row-tile, ch = K-chunk of 256. Partials to P.
// ---------------------------------------------------------------------------
__global__ __launch_bounds__(256)
void xproj_split(const u16* __restrict__ A, const u16* __restrict__ BT,
                 float* __restrict__ P) {
  __shared__ u16 As[128][64];
  __shared__ u16 Bs[128][64];
  const int t = threadIdx.x;
  const int l = t & 63;
  const int w = t >> 6;
  const int wr = (w >> 1) * 64;
  const int wc = (w & 1) * 64;
  const int bx = blockIdx.x;
  const int ch = blockIdx.y;
  const int kb = ch * 256;

  const size_t aoff = (size_t)bx * 128 * 2048 + kb;
  const int r0 = t >> 3;
  const int c0s = (((t & 7) ^ (r0 & 7)) << 3);
  const int c0l = (t & 7) << 3;
  const int lr = l & 15;
  const int lq = l >> 4;

  f32x4 acc[4][4];
#pragma unroll
  for (int i = 0; i < 4; ++i)
#pragma unroll
    for (int j = 0; j < 4; ++j) acc[i][j] = (f32x4){0.f, 0.f, 0.f, 0.f};

  for (int kt = 0; kt < 256; kt += 64) {
    __syncthreads();
#pragma unroll
    for (int i = 0; i < 4; ++i) {
      const int r = r0 + i * 32;
      gload_lds16(A + aoff + (size_t)r * 2048 + kt + c0s, &As[r][c0l]);
      gload_lds16(BT + (size_t)r * 2048 + kb + kt + c0s, &Bs[r][c0l]);
    }
    __syncthreads();
#pragma unroll
    for (int kk = 0; kk < 2; ++kk) {
      bf16x8 af[4], bfr[4];
#pragma unroll
      for (int i = 0; i < 4; ++i) {
        const int row = wr + i * 16 + lr;
        af[i] = *(const bf16x8*)&As[row][(((kk << 2) | lq) ^ (row & 7)) << 3];
      }
#pragma unroll
      for (int j = 0; j < 4; ++j) {
        const int row = wc + j * 16 + lr;
        bfr[j] = *(const bf16x8*)&Bs[row][(((kk << 2) | lq) ^ (row & 7)) << 3];
      }
#pragma unroll
      for (int i = 0; i < 4; ++i)
#pragma unroll
        for (int j = 0; j < 4; ++j)
          acc[i][j] = __builtin_amdgcn_mfma_f32_16x16x32_bf16(af[i], bfr[j], acc[i][j], 0, 0, 0);
    }
  }

  float* __restrict__ Pc = P + (size_t)ch * 262144;
  const int lg4 = lq * 4;
#pragma unroll
  for (int i = 0; i < 4; ++i) {
    const int grow0 = bx * 128 + wr + i * 16 + lg4;
#pragma unroll
    for (int j = 0; j < 4; ++j) {
      const int gcol = wc + j * 16 + lr;
#pragma unroll
      for (int r = 0; r < 4; ++r)
        Pc[(size_t)(grow0 + r) * 128 + gcol] = acc[i][j][r];
    }
  }
}

// merge 8 x_proj partials -> dbc f32 (2048x128) + dtbf bf16 (cols<64)
__global__ __launch_bounds__(256)
void merge_x(const float* __restrict__ P, float* __restrict__ dbc,
             u16* __restrict__ dtbf) {
  const int idx = blockIdx.x * 256 + threadIdx.x;   // 262144
  float s = 0.f;
#pragma unroll
  for (int ch = 0; ch < 8; ++ch) s += P[(size_t)ch * 262144 + idx];
  dbc[idx] = s;
  const int c = idx & 127, r = idx >> 7;
  if (c < 64) dtbf[r * 64 + c] = f2bf(s);
}

// ---------------------------------------------------------------------------
// out_proj split-K: A=ybf[2048,2048], BT=WoT[1024,2048] (ld 2048).
// grid (16, 16): bx = row-tile, y&7 = N-tile, y>>3 = K-half. Partials to P.
// ---------------------------------------------------------------------------
__global__ __launch_bounds__(256)
void outproj_split(const u16* __restrict__ A, const u16* __restrict__ BT,
                   float* __restrict__ P) {
  __shared__ u16 As[128][64];
  __shared__ u16 Bs[128][64];
  const int t = threadIdx.x;
  const int l = t & 63;
  const int w = t >> 6;
  const int wr = (w >> 1) * 64;
  const int wc = (w & 1) * 64;
  const int bx = blockIdx.x;
  const int byn = blockIdx.y & 7;
  const int ch = blockIdx.y >> 3;
  const int kb = ch * 1024;

  const size_t aoff = (size_t)bx * 128 * 2048 + kb;
  const size_t boff = (size_t)byn * 128 * 2048 + kb;
  const int r0 = t >> 3;
  const int c0s = (((t & 7) ^ (r0 & 7)) << 3);
  const int c0l = (t & 7) << 3;
  const int lr = l & 15;
  const int lq = l >> 4;

  f32x4 acc[4][4];
#pragma unroll
  for (int i = 0; i < 4; ++i)
#pragma unroll
    for (int j = 0; j < 4; ++j) acc[i][j] = (f32x4){0.f, 0.f, 0.f, 0.f};

  for (int kt = 0; kt < 1024; kt += 64) {
    __syncthreads();
#pragma unroll
    for (int i = 0; i < 4; ++i) {
      const int r = r0 + i * 32;
      gload_lds16(A + aoff + (size_t)r * 2048 + kt + c0s, &As[r][c0l]);
      gload_lds16(BT + boff + (size_t)r * 2048 + kt + c0s, &Bs[r][c0l]);
    }
    __syncthreads();
#pragma unroll
    for (int kk = 0; kk < 2; ++kk) {
      bf16x8 af[4], bfr[4];
#pragma unroll
      for (int i = 0; i < 4; ++i) {
        const int row = wr + i * 16 + lr;
        af[i] = *(const bf16x8*)&As[row][(((kk << 2) | lq) ^ (row & 7)) << 3];
      }
#pragma unroll
      for (int j = 0; j < 4; ++j) {
        const int row = wc + j * 16 + lr;
        bfr[j] = *(const bf16x8*)&Bs[row][(((kk << 2) | lq) ^ (row & 7)) << 3];
      }
#pragma unroll
      for (int i = 0; i < 4; ++i)
#pragma unroll
        for (int j = 0; j < 4; ++j)
          acc[i][j] = __builtin_amdgcn_mfma_f32_16x16x32_bf16(af[i], bfr[j], acc[i][j], 0, 0, 0);
    }
  }

  float* __restrict__ Pc = P + (size_t)ch * 2097152;
  const int lg4 = lq * 4;
#pragma unroll
  for (int i = 0; i < 4; ++i) {
    const int grow0 = bx * 128 + wr + i * 16 + lg4;
#pragma unroll
    for (int j = 0; j < 4; ++j) {
      const int gcol = byn * 128 + wc + j * 16 + lr;
#pragma unroll
      for (int r = 0; r < 4; ++r)
        Pc[(size_t)(grow0 + r) * 1024 + gcol] = acc[i][j][r];
    }
  }
}

// layer-1 merge: xbf = bf16(p0 + p1)
__global__ __launch_bounds__(256)
void merge_o1(const float* __restrict__ P, u16* __restrict__ xbf) {
  const int i4 = (blockIdx.x * 256 + threadIdx.x) * 4;   // 2048 blocks
  const float4 a = *(const float4*)(P + i4);
  const float4 b = *(const float4*)(P + 2097152 + i4);
  u16x4 o = { f2bf(a.x + b.x), f2bf(a.y + b.y), f2bf(a.z + b.z), f2bf(a.w + b.w) };
  *(u16x4*)(xbf + i4) = o;
}

// layer-2 merge + final LayerNorm fused: xlnbf = bf16(LN(p0+p1))
__global__ __launch_bounds__(256)
void merge_o2_ln(const float* __restrict__ P, const float* __restrict__ g,
                 const float* __restrict__ bta, u16* __restrict__ out) {
  __shared__ float red1[4], red2[4];
  const int r = blockIdx.x;
  const int tid = threadIdx.x;
  const int lane = tid & 63, wid = tid >> 6;
  const int c4 = tid * 4;
  const float4 a = *(const float4*)(P + (size_t)r * 1024 + c4);
  const float4 b = *(const float4*)(P + 2097152 + (size_t)r * 1024 + c4);
  float4 v = { a.x + b.x, a.y + b.y, a.z + b.z, a.w + b.w };
  float s = v.x + v.y + v.z + v.w;
#pragma unroll
  for (int m = 1; m < 64; m <<= 1) s += __shfl_xor(s, m, 64);
  if (lane == 0) red1[wid] = s;
  __syncthreads();
  const float mu = (red1[0] + red1[1] + red1[2] + red1[3]) * (1.f / 1024.f);
  const float d0 = v.x - mu, d1 = v.y - mu, d2 = v.z - mu, d3 = v.w - mu;
  float q = d0 * d0 + d1 * d1 + d2 * d2 + d3 * d3;
#pragma unroll
  for (int m = 1; m < 64; m <<= 1) q += __shfl_xor(q, m, 64);
  if (lane == 0) red2[wid] = q;
  __syncthreads();
  const float rs = rsqrtf((red2[0] + red2[1] + red2[2] + red2[3]) * (1.f / 1024.f) + 1e-5f);
  const float4 gv = *(const float4*)(g + c4);
  const float4 bv = *(const float4*)(bta + c4);
  u16x4 o = { f2bf(d0 * rs * gv.x + bv.x), f2bf(d1 * rs * gv.y + bv.y),
              f2bf(d2 * rs * gv.z + bv.z), f2bf(d3 * rs * gv.w + bv.w) };
  *(u16x4*)(out + (size_t)r * 1024 + c4) = o;
}

// ---------------------------------------------------------------------------
// batched transpose+convert: f32 (K,N) -> bf16 (Npad,K), zero-pad n>=N.
// ---------------------------------------------------------------------------
struct TBatch {
  const float* src[5];
  u16* dst[5];
  int K[5], N[5], tx[5];
  int start[6];
  int njobs;
};

__global__ __launch_bounds__(256)
void transpose_batch(TBatch tb) {
  const int tile = blockIdx.x;
  int j = 0;
  while (j + 1 < tb.njobs && tile >= tb.start[j + 1]) ++j;
  const int lt = tile - tb.start[j];
  const int K = tb.K[j];
  const int N = tb.N[j];
  const int kb = (lt % tb.tx[j]) * 32;
  const int nb = (lt / tb.tx[j]) * 32;
  const float* __restrict__ in = tb.src[j];
  u16* __restrict__ out = tb.dst[j];

  __shared__ float tile_s[32][33];
  const int tx = threadIdx.x & 31;
  const int ty = threadIdx.x >> 5;
#pragma unroll
  for (int s = 0; s < 4; ++s) {
    const int k = kb + ty + s * 8;
    const int n = nb + tx;
    tile_s[ty + s * 8][tx] = (n < N) ? in[(size_t)k * N + n] : 0.f;
  }
  __syncthreads();
#pragma unroll
  for (int s = 0; s < 4; ++s) {
    const int n = nb + ty + s * 8;
    const int k = kb + tx;
    out[(size_t)n * K + k] = f2bf(tile_s[tx][ty + s * 8]);
  }
}

__global__ __launch_bounds__(256)
void embed_gather(const int* __restrict__ ids, const float* __restrict__ embed,
                  u16* __restrict__ xbf) {
  const int r = blockIdx.x;
  const int c = threadIdx.x * 4;
  const int id = ids[r];
  const float4 v = *(const float4*)(embed + (size_t)id * 1024 + c);
  u16x4 o = { f2bf(v.x), f2bf(v.y), f2bf(v.z), f2bf(v.w) };
  *(u16x4*)(xbf + (size_t)r * 1024 + c) = o;
}

// u = silu(causal_conv(xin) + cb), 4 channels per thread (float4 path)
__global__ __launch_bounds__(256)
void conv_silu4(const float* __restrict__ xz, const float* __restrict__ cw,
                const float* __restrict__ cb, float* __restrict__ u,
                u16* __restrict__ ubf) {
  const int i4 = (blockIdx.x * 256 + threadIdx.x) * 4;   // grid 4096
  const int d = i4 & 2047;
  const int r = i4 >> 11;
  const int t = r & 1023;
  float4 acc = *(const float4*)(cb + d);
  const float4 w0 = *(const float4*)(cw + (d + 0) * 4);
  const float4 w1 = *(const float4*)(cw + (d + 1) * 4);
  const float4 w2 = *(const float4*)(cw + (d + 2) * 4);
  const float4 w3 = *(const float4*)(cw + (d + 3) * 4);
#pragma unroll
  for (int k = 0; k < 4; ++k) {
    const int tt = t - 3 + k;
    if (tt >= 0) {
      const float4 x4 = *(const float4*)(xz + (size_t)(r - 3 + k) * 4096 + d);
      acc.x = fmaf(x4.x, ((const float*)&w0)[k], acc.x);
      acc.y = fmaf(x4.y, ((const float*)&w1)[k], acc.y);
      acc.z = fmaf(x4.z, ((const float*)&w2)[k], acc.z);
      acc.w = fmaf(x4.w, ((const float*)&w3)[k], acc.w);
    }
  }
  const float4 s = { acc.x / (1.f + __expf(-acc.x)), acc.y / (1.f + __expf(-acc.y)),
                     acc.z / (1.f + __expf(-acc.z)), acc.w / (1.f + __expf(-acc.w)) };
  *(float4*)(u + i4) = s;
  u16x4 o = { f2bf(s.x), f2bf(s.y), f2bf(s.z), f2bf(s.w) };
  *(u16x4*)(ubf + i4) = o;
}

// ---------------------------------------------------------------------------
// chunked selective scan: 8 chunks x 128 steps (pass1 local, pass2 global+y)
// ---------------------------------------------------------------------------
__global__ __launch_bounds__(256)
void scan_pass1(const float* __restrict__ delta, const float* __restrict__ u,
                const float* __restrict__ dbc, const float* __restrict__ A_log,
                float* __restrict__ Pb, float* __restrict__ Qb) {
  const int blk = blockIdx.x;
  const int ch = blk & 7;
  const int dt16 = (blk >> 3) & 127;
  const int b = blk >> 10;
  const int n = threadIdx.x & 15;
  const int dl = threadIdx.x >> 4;
  const int d = dt16 * 16 + dl;
  const float Ac = -expf(A_log[d * 16 + n]) * 1.44269504f;
  const int r0 = b * 1024 + ch * 128;
  float P = 1.f, h = 0.f;
  for (int j = 0; j < 128; ++j) {
    const size_t r = r0 + j;
    const float dlt = delta[r * 2048 + d];
    const float uu = u[r * 2048 + d];
    const float Bv = dbc[r * 128 + 64 + n];
    const float da = exp2f(dlt * Ac);
    P *= da;
    h = fmaf(da, h, dlt * uu * Bv);
  }
  const size_t idx = ((size_t)(b * 2048 + d) * 16 + n) * 8 + ch;
  Pb[idx] = P;
  Qb[idx] = h;
}

__global__ __launch_bounds__(256)
void scan_pass2(const float* __restrict__ delta, const float* __restrict__ u,
                const float* __restrict__ dbc, const float* __restrict__ xz,
                const float* __restrict__ A_log, const float* __restrict__ Dp,
                const float* __restrict__ Pb, const float* __restrict__ Qb,
                u16* __restrict__ ybf) {
  const int blk = blockIdx.x;
  const int ch = blk & 7;
  const int dt16 = (blk >> 3) & 127;
  const int b = blk >> 10;
  const int n = threadIdx.x & 15;
  const int dl = threadIdx.x >> 4;
  const int d = dt16 * 16 + dl;
  const float Ac = -expf(A_log[d * 16 + n]) * 1.44269504f;
  const float Dd = Dp[d];
  const int r0 = b * 1024 + ch * 128;

  float h = 0.f;
  const size_t p0 = ((size_t)(b * 2048 + d) * 16 + n) * 8;
  for (int cc = 0; cc < ch; ++cc) h = fmaf(Pb[p0 + cc], h, Qb[p0 + cc]);

  for (int j = 0; j < 128; ++j) {
    const size_t r = r0 + j;
    const float dlt = delta[r * 2048 + d];
    const float uu = u[r * 2048 + d];
    const float Bv = dbc[r * 128 + 64 + n];
    const float Cv = dbc[r * 128 + 80 + n];
    const float da = exp2f(dlt * Ac);
    h = fmaf(da, h, dlt * uu * Bv);
    float p = rowsum16(h * Cv);
    if (n == 0) {
      const float zz = xz[r * 4096 + 2048 + d];
      const float yv = (p + uu * Dd) * (zz / (1.f + __expf(-zz)));
      ybf[r * 2048 + d] = f2bf(yv);
    }
  }
}

// ---------------------------------------------------------------------------
extern "C" void kernel_launch(void* const* d_in, const int* in_sizes, int n_in,
                              void* d_out, int out_size, void* d_ws, size_t ws_size,
                              hipStream_t stream) {
  (void)in_sizes; (void)n_in; (void)out_size; (void)ws_size;
  const int*   ids      = (const int*)d_in[0];
  const float* embed    = (const float*)d_in[1];
  const float* in_proj  = (const float*)d_in[2];
  const float* conv_w   = (const float*)d_in[3];
  const float* conv_b   = (const float*)d_in[4];
  const float* x_proj   = (const float*)d_in[5];
  const float* dt_w     = (const float*)d_in[6];
  const float* dt_b     = (const float*)d_in[7];
  const float* A_log    = (const float*)d_in[8];
  const float* Dp       = (const float*)d_in[9];
  const float* out_proj = (const float*)d_in[10];
  const float* ln_g     = (const float*)d_in[11];
  const float* ln_bta   = (const float*)d_in[12];
  const float* head     = (const float*)d_in[13];

  // f32 scratch inside d_out (all consumed before head GEMM overwrites)
  float* fout = (float*)d_out;
  float* xz   = fout;              // 2048*4096
  float* ubuf = fout + 8388608;    // 2048*2048
  float* dbuf = fout + 12582912;   // 2048*2048 (delta)
  float* dbc  = fout + 16777216;   // 2048*128
  float* Pb   = fout + 19136512;   // 524288
  float* Qb   = fout + 19660800;   // 524288
  float* xpp  = fout + 20185088;   // 8 * 2048*128  = 2097152
  float* opp  = fout + 22282240;   // 2 * 2048*1024 = 4194304 (ends 26476544)

  // bf16 scratch in d_ws
  char* wp = (char*)d_ws;
  u16* headT = (u16*)wp; wp += (size_t)32000 * 1024 * 2;
  u16* WiT   = (u16*)wp; wp += (size_t)4096 * 1024 * 2;
  u16* WxT   = (u16*)wp; wp += (size_t)128 * 2048 * 2;
  u16* WdtT  = (u16*)wp; wp += (size_t)2048 * 64 * 2;
  u16* WoT   = (u16*)wp; wp += (size_t)1024 * 2048 * 2;
  u16* xbf   = (u16*)wp; wp += (size_t)2048 * 1024 * 2;
  u16* ubf   = (u16*)wp; wp += (size_t)2048 * 2048 * 2;
  u16* dtbf  = (u16*)wp; wp += (size_t)2048 * 64 * 2;
  u16* ybf   = (u16*)wp; wp += (size_t)2048 * 2048 * 2;
  u16* xlnbf = (u16*)wp; wp += (size_t)2048 * 1024 * 2;

  const dim3 tb(256);
  const dim3 tb5(512);
  embed_gather<<<2048, tb, 0, stream>>>(ids, embed, xbf);

  for (int i = 0; i < 2; ++i) {
    TBatch t{};
    int nj = 0, acc = 0;
    if (i == 0) {
      t.src[nj] = head; t.dst[nj] = headT;
      t.K[nj] = 1024; t.N[nj] = 32000; t.tx[nj] = 32;
      t.start[nj] = acc; acc += 32 * 1000; ++nj;
    }
    t.src[nj] = in_proj + (size_t)i * 1024 * 4096; t.dst[nj] = WiT;
    t.K[nj] = 1024; t.N[nj] = 4096; t.tx[nj] = 32;
    t.start[nj] = acc; acc += 32 * 128; ++nj;
    t.src[nj] = x_proj + (size_t)i * 2048 * 96; t.dst[nj] = WxT;
    t.K[nj] = 2048; t.N[nj] = 96; t.tx[nj] = 64;
    t.start[nj] = acc; acc += 64 * 4; ++nj;
    t.src[nj] = dt_w + (size_t)i * 64 * 2048; t.dst[nj] = WdtT;
    t.K[nj] = 64; t.N[nj] = 2048; t.tx[nj] = 2;
    t.start[nj] = acc; acc += 2 * 64; ++nj;
    t.src[nj] = out_proj + (size_t)i * 2048 * 1024; t.dst[nj] = WoT;
    t.K[nj] = 2048; t.N[nj] = 1024; t.tx[nj] = 64;
    t.start[nj] = acc; acc += 64 * 32; ++nj;
    t.start[nj] = acc;
    t.njobs = nj;
    transpose_batch<<<acc, tb, 0, stream>>>(t);

    gemm_bt<0><<<dim3(16, 32), tb, 0, stream>>>(xbf, WiT, xz, nullptr, nullptr, 2048, 4096, 1024);
    conv_silu4<<<4096, tb, 0, stream>>>(xz, conv_w + i * 2048 * 4, conv_b + i * 2048, ubuf, ubf);
    xproj_split<<<dim3(16, 8), tb, 0, stream>>>(ubf, WxT, xpp);
    merge_x<<<1024, tb, 0, stream>>>(xpp, dbc, dtbf);
    gemm_bt<1><<<dim3(16, 16), tb, 0, stream>>>(dtbf, WdtT, dbuf, nullptr, dt_b + i * 2048, 2048, 2048, 64);
    scan_pass1<<<2048, tb, 0, stream>>>(dbuf, ubuf, dbc, A_log + i * 2048 * 16, Pb, Qb);
    scan_pass2<<<2048, tb, 0, stream>>>(dbuf, ubuf, dbc, xz, A_log + i * 2048 * 16, Dp + i * 2048, Pb, Qb, ybf);
    outproj_split<<<dim3(16, 16), tb, 0, stream>>>(ybf, WoT, opp);
    if (i == 0) {
      merge_o1<<<2048, tb, 0, stream>>>(opp, xbf);
    } else {
      merge_o2_ln<<<2048, tb, 0, stream>>>(opp, ln_g, ln_bta, xlnbf);
    }
  }

  gemm256<0><<<dim3(8, 125), tb5, 0, stream>>>(xlnbf, headT, fout, nullptr, nullptr, 2048, 32000, 1024);
}

// Round 7
// 722.757 us; speedup vs baseline: 1.2900x; 1.0237x over previous
//
#include <hip/hip_runtime.h>

typedef unsigned short u16;
typedef __attribute__((ext_vector_type(8))) short bf16x8;
typedef __attribute__((ext_vector_type(4))) float f32x4;
typedef __attribute__((ext_vector_type(4))) u16 u16x4;

#define DEV static __device__ __forceinline__

DEV u16 f2bf(float f) {
  union { float f; unsigned u; } v; v.f = f;
  unsigned r = (v.u + 0x7fffu + ((v.u >> 16) & 1u)) >> 16;
  return (u16)r;
}

DEV void gload_lds16(const void* g, void* l) {
  __builtin_amdgcn_global_load_lds(
      (const __attribute__((address_space(1))) unsigned int*)g,
      (__attribute__((address_space(3))) unsigned int*)l, 16, 0, 0);
}

// sum over each aligned 16-lane group via DPP row rotations (pure VALU)
DEV float rowsum16(float p) {
  p += __int_as_float(__builtin_amdgcn_update_dpp(0, __float_as_int(p), 0x128, 0xF, 0xF, true)); // ror:8
  p += __int_as_float(__builtin_amdgcn_update_dpp(0, __float_as_int(p), 0x124, 0xF, 0xF, true)); // ror:4
  p += __int_as_float(__builtin_amdgcn_update_dpp(0, __float_as_int(p), 0x122, 0xF, 0xF, true)); // ror:2
  p += __int_as_float(__builtin_amdgcn_update_dpp(0, __float_as_int(p), 0x121, 0xF, 0xF, true)); // ror:1
  return p;
}

// ---------------------------------------------------------------------------
// 256x256 8-wave MFMA GEMM — m201 8-phase (HEAD GEMM only).
// C stored NON-TEMPORAL (never re-read; keeps B resident in L3).
// ---------------------------------------------------------------------------
#define STGH(buf, mat, half, P, kt) { \
    const int r_ = (half) * 128 + sr0; \
    gload_lds16((P) + (size_t)r_ * K + (kt) + scs, &lds[buf][mat][r_][sc8]); \
    gload_lds16((P) + (size_t)(r_ + 64) * K + (kt) + scs, &lds[buf][mat][r_ + 64][sc8]); }
#define LDB(buf) _Pragma("unroll") for (int n = 0; n < 4; ++n) { \
    const int row = wn * 64 + n * 16 + lr; \
    _Pragma("unroll") for (int kk = 0; kk < 2; ++kk) \
      bfr[n][kk] = *(const bf16x8*)&lds[buf][1][row][(((kk << 2) | lq) ^ (row & 7)) << 3]; }
#define LDA(buf, p) _Pragma("unroll") for (int mi = 0; mi < 2; ++mi) { \
    const int row = wm * 128 + ((p) * 2 + mi) * 16 + lr; \
    _Pragma("unroll") for (int kk = 0; kk < 2; ++kk) \
      af[mi][kk] = *(const bf16x8*)&lds[buf][0][row][(((kk << 2) | lq) ^ (row & 7)) << 3]; }
#define MM(p) __builtin_amdgcn_s_setprio(1); \
  _Pragma("unroll") for (int kk = 0; kk < 2; ++kk) \
  _Pragma("unroll") for (int mi = 0; mi < 2; ++mi) \
  _Pragma("unroll") for (int n = 0; n < 4; ++n) \
    acc[(p) * 2 + mi][n] = __builtin_amdgcn_mfma_f32_16x16x32_bf16(af[mi][kk], bfr[n][kk], acc[(p) * 2 + mi][n], 0, 0, 0); \
  __builtin_amdgcn_s_setprio(0);
#define BAR() { __builtin_amdgcn_s_barrier(); asm volatile("" ::: "memory"); }
#define WLG() { asm volatile("s_waitcnt lgkmcnt(0)" ::: "memory"); __builtin_amdgcn_sched_barrier(0); }
#define VMC(n) asm volatile("s_waitcnt vmcnt(" #n ")" ::: "memory")

__global__ __launch_bounds__(512, 1)
void gemm256(const u16* __restrict__ A, const u16* __restrict__ BT,
             float* __restrict__ C, int M, int N, int K) {
  __shared__ u16 lds[2][2][256][64];   // [buf][A=0,B=1][row][k]
  const int t = threadIdx.x;
  const int l = t & 63;
  const int w = t >> 6;
  const int wm = w >> 2;        // 0..1
  const int wn = w & 3;         // 0..3
  const int lr = l & 15, lq = l >> 4;

  const int gn = N >> 8;
  const int nwg = gn << 3;
  const int orig = blockIdx.y * 8 + blockIdx.x;
  const int q = nwg >> 3;
  const int swz = (orig & 7) * q + (orig >> 3);
  const int bx = swz & 7;
  const int by = swz >> 3;

  const u16* Ap = A + (size_t)bx * 256 * K;
  const u16* Bp = BT + (size_t)by * 256 * K;
  const int sr0 = t >> 3;
  const int sc8 = (t & 7) << 3;
  const int scs = (((t & 7) ^ (sr0 & 7)) << 3);

  f32x4 acc[8][4];
#pragma unroll
  for (int m = 0; m < 8; ++m)
#pragma unroll
    for (int n = 0; n < 4; ++n) acc[m][n] = (f32x4){0.f, 0.f, 0.f, 0.f};

  const int NI = K >> 7;
  STGH(0, 1, 0, Bp, 0) STGH(0, 1, 1, Bp, 0)
  STGH(0, 0, 0, Ap, 0) STGH(0, 0, 1, Ap, 0)
  STGH(1, 1, 0, Bp, 64) STGH(1, 1, 1, Bp, 64)
  VMC(4);
  BAR();

  for (int ip = 0; ip < NI; ++ip) {
    const int k0 = ip << 7;
    const bool m2 = (k0 + 128) < K;
    const bool m3 = (k0 + 192) < K;
    bf16x8 bfr[4][2], af[2][2];
    LDB(0) LDA(0, 0)
    STGH(1, 0, 0, Ap, k0 + 64)
    BAR(); WLG(); MM(0) BAR();
    LDA(0, 1)
    STGH(1, 0, 1, Ap, k0 + 64)
    BAR(); WLG(); MM(1) BAR();
    LDA(0, 2)
    if (m2) STGH(0, 1, 0, Bp, k0 + 128)
    BAR(); WLG(); MM(2) BAR();
    LDA(0, 3)
    if (m2) STGH(0, 1, 1, Bp, k0 + 128)
    BAR(); WLG(); MM(3)
    if (m2) { VMC(4); } else { VMC(0); }
    BAR();
    LDB(1) LDA(1, 0)
    if (m2) STGH(0, 0, 0, Ap, k0 + 128)
    BAR(); WLG(); MM(0) BAR();
    LDA(1, 1)
    if (m2) STGH(0, 0, 1, Ap, k0 + 128)
    BAR(); WLG(); MM(1) BAR();
    LDA(1, 2)
    if (m3) STGH(1, 1, 0, Bp, k0 + 192)
    BAR(); WLG(); MM(2) BAR();
    LDA(1, 3)
    if (m3) STGH(1, 1, 1, Bp, k0 + 192)
    BAR(); WLG(); MM(3)
    if (m3) { VMC(4); } else { VMC(0); }
    BAR();
  }

  const int lg4 = lq * 4;
#pragma unroll
  for (int m = 0; m < 8; ++m) {
    const int grow0 = bx * 256 + wm * 128 + m * 16 + lg4;
#pragma unroll
    for (int n = 0; n < 4; ++n) {
      const int gcol = by * 256 + wn * 64 + n * 16 + lr;
#pragma unroll
      for (int r = 0; r < 4; ++r) {
        const size_t idx = (size_t)(grow0 + r) * N + gcol;
        __builtin_nontemporal_store(acc[m][n][r], &C[idx]);
      }
    }
  }
}
#undef STGH
#undef LDB
#undef LDA
#undef MM
#undef BAR
#undef WLG
#undef VMC

// ---------------------------------------------------------------------------
// 128x128 BK=64 GEMM.  EPI: 0 = f32; 1 = +bias, softplus, f32.
// gridDim.x MUST be 16; nwg % 8 == 0.
// ---------------------------------------------------------------------------
template<int EPI>
__global__ __launch_bounds__(256)
void gemm_bt(const u16* __restrict__ A, const u16* __restrict__ BT,
             float* __restrict__ C, u16* __restrict__ Cbf,
             const float* __restrict__ bias, int M, int N, int K) {
  __shared__ u16 As[128][64];
  __shared__ u16 Bs[128][64];
  const int t = threadIdx.x;
  const int l = t & 63;
  const int w = t >> 6;
  const int wr = (w >> 1) * 64;
  const int wc = (w & 1) * 64;

  const int nwg = gridDim.x * gridDim.y;
  const int orig = blockIdx.y * gridDim.x + blockIdx.x;
  const int swz = (orig & 7) * (nwg >> 3) + (orig >> 3);
  const int bx = swz & 15;
  const int by = swz >> 4;

  const size_t aoff = (size_t)bx * 128 * K;
  const size_t boff = (size_t)by * 128 * K;
  const int r0 = t >> 3;
  const int c0s = (((t & 7) ^ (r0 & 7)) << 3);
  const int c0l = (t & 7) << 3;
  const int lr = l & 15;
  const int lq = l >> 4;

  f32x4 acc[4][4];
#pragma unroll
  for (int i = 0; i < 4; ++i)
#pragma unroll
    for (int j = 0; j < 4; ++j) acc[i][j] = (f32x4){0.f, 0.f, 0.f, 0.f};

  for (int kt = 0; kt < K; kt += 64) {
    __syncthreads();
#pragma unroll
    for (int i = 0; i < 4; ++i) {
      const int r = r0 + i * 32;
      gload_lds16(A + aoff + (size_t)r * K + kt + c0s, &As[r][c0l]);
      gload_lds16(BT + boff + (size_t)r * K + kt + c0s, &Bs[r][c0l]);
    }
    __syncthreads();
#pragma unroll
    for (int kk = 0; kk < 2; ++kk) {
      bf16x8 af[4], bfr[4];
#pragma unroll
      for (int i = 0; i < 4; ++i) {
        const int row = wr + i * 16 + lr;
        af[i] = *(const bf16x8*)&As[row][(((kk << 2) | lq) ^ (row & 7)) << 3];
      }
#pragma unroll
      for (int j = 0; j < 4; ++j) {
        const int row = wc + j * 16 + lr;
        bfr[j] = *(const bf16x8*)&Bs[row][(((kk << 2) | lq) ^ (row & 7)) << 3];
      }
#pragma unroll
      for (int i = 0; i < 4; ++i)
#pragma unroll
        for (int j = 0; j < 4; ++j)
          acc[i][j] = __builtin_amdgcn_mfma_f32_16x16x32_bf16(af[i], bfr[j], acc[i][j], 0, 0, 0);
    }
  }

  const int lg4 = lq * 4;
#pragma unroll
  for (int i = 0; i < 4; ++i) {
    const int grow0 = bx * 128 + wr + i * 16 + lg4;
#pragma unroll
    for (int j = 0; j < 4; ++j) {
      const int gcol = by * 128 + wc + j * 16 + lr;
      float bv = 0.f;
      if (EPI == 1) bv = bias[gcol];
#pragma unroll
      for (int r = 0; r < 4; ++r) {
        float v = acc[i][j][r];
        if (EPI == 1) {
          v += bv;
          v = fmaxf(v, 0.f) + log1pf(expf(-fabsf(v)));   // stable softplus
        }
        C[(size_t)(grow0 + r) * N + gcol] = v;
      }
    }
  }
}

// ---------------------------------------------------------------------------
// x_proj split-K: A=ubf[2048,2048], BT=WxT[128,2048] (both ld 2048).
// grid (16, 8): bx = row-tile, ch = K-chunk of 256. Partials to P.
// ---------------------------------------------------------------------------
__global__ __launch_bounds__(256)
void xproj_split(const u16* __restrict__ A, const u16* __restrict__ BT,
                 float* __restrict__ P) {
  __shared__ u16 As[128][64];
  __shared__ u16 Bs[128][64];
  const int t = threadIdx.x;
  const int l = t & 63;
  const int w = t >> 6;
  const int wr = (w >> 1) * 64;
  const int wc = (w & 1) * 64;
  const int bx = blockIdx.x;
  const int ch = blockIdx.y;
  const int kb = ch * 256;

  const size_t aoff = (size_t)bx * 128 * 2048 + kb;
  const int r0 = t >> 3;
  const int c0s = (((t & 7) ^ (r0 & 7)) << 3);
  const int c0l = (t & 7) << 3;
  const int lr = l & 15;
  const int lq = l >> 4;

  f32x4 acc[4][4];
#pragma unroll
  for (int i = 0; i < 4; ++i)
#pragma unroll
    for (int j = 0; j < 4; ++j) acc[i][j] = (f32x4){0.f, 0.f, 0.f, 0.f};

  for (int kt = 0; kt < 256; kt += 64) {
    __syncthreads();
#pragma unroll
    for (int i = 0; i < 4; ++i) {
      const int r = r0 + i * 32;
      gload_lds16(A + aoff + (size_t)r * 2048 + kt + c0s, &As[r][c0l]);
      gload_lds16(BT + (size_t)r * 2048 + kb + kt + c0s, &Bs[r][c0l]);
    }
    __syncthreads();
#pragma unroll
    for (int kk = 0; kk < 2; ++kk) {
      bf16x8 af[4], bfr[4];
#pragma unroll
      for (int i = 0; i < 4; ++i) {
        const int row = wr + i * 16 + lr;
        af[i] = *(const bf16x8*)&As[row][(((kk << 2) | lq) ^ (row & 7)) << 3];
      }
#pragma unroll
      for (int j = 0; j < 4; ++j) {
        const int row = wc + j * 16 + lr;
        bfr[j] = *(const bf16x8*)&Bs[row][(((kk << 2) | lq) ^ (row & 7)) << 3];
      }
#pragma unroll
      for (int i = 0; i < 4; ++i)
#pragma unroll
        for (int j = 0; j < 4; ++j)
          acc[i][j] = __builtin_amdgcn_mfma_f32_16x16x32_bf16(af[i], bfr[j], acc[i][j], 0, 0, 0);
    }
  }

  float* __restrict__ Pc = P + (size_t)ch * 262144;
  const int lg4 = lq * 4;
#pragma unroll
  for (int i = 0; i < 4; ++i) {
    const int grow0 = bx * 128 + wr + i * 16 + lg4;
#pragma unroll
    for (int j = 0; j < 4; ++j) {
      const int gcol = wc + j * 16 + lr;
#pragma unroll
      for (int r = 0; r < 4; ++r)
        Pc[(size_t)(grow0 + r) * 128 + gcol] = acc[i][j][r];
    }
  }
}

// merge 8 x_proj partials -> dbc f32 (2048x128) + dtbf bf16 (cols<64)
__global__ __launch_bounds__(256)
void merge_x(const float* __restrict__ P, float* __restrict__ dbc,
             u16* __restrict__ dtbf) {
  const int idx = blockIdx.x * 256 + threadIdx.x;   // 262144
  float s = 0.f;
#pragma unroll
  for (int ch = 0; ch < 8; ++ch) s += P[(size_t)ch * 262144 + idx];
  dbc[idx] = s;
  const int c = idx & 127, r = idx >> 7;
  if (c < 64) dtbf[r * 64 + c] = f2bf(s);
}

// ---------------------------------------------------------------------------
// out_proj split-K: A=ybf[2048,2048], BT=WoT[1024,2048] (ld 2048).
// grid (16, 16): bx = row-tile, y&7 = N-tile, y>>3 = K-half. Partials to P.
// ---------------------------------------------------------------------------
__global__ __launch_bounds__(256)
void outproj_split(const u16* __restrict__ A, const u16* __restrict__ BT,
                   float* __restrict__ P) {
  __shared__ u16 As[128][64];
  __shared__ u16 Bs[128][64];
  const int t = threadIdx.x;
  const int l = t & 63;
  const int w = t >> 6;
  const int wr = (w >> 1) * 64;
  const int wc = (w & 1) * 64;
  const int bx = blockIdx.x;
  const int byn = blockIdx.y & 7;
  const int ch = blockIdx.y >> 3;
  const int kb = ch * 1024;

  const size_t aoff = (size_t)bx * 128 * 2048 + kb;
  const size_t boff = (size_t)byn * 128 * 2048 + kb;
  const int r0 = t >> 3;
  const int c0s = (((t & 7) ^ (r0 & 7)) << 3);
  const int c0l = (t & 7) << 3;
  const int lr = l & 15;
  const int lq = l >> 4;

  f32x4 acc[4][4];
#pragma unroll
  for (int i = 0; i < 4; ++i)
#pragma unroll
    for (int j = 0; j < 4; ++j) acc[i][j] = (f32x4){0.f, 0.f, 0.f, 0.f};

  for (int kt = 0; kt < 1024; kt += 64) {
    __syncthreads();
#pragma unroll
    for (int i = 0; i < 4; ++i) {
      const int r = r0 + i * 32;
      gload_lds16(A + aoff + (size_t)r * 2048 + kt + c0s, &As[r][c0l]);
      gload_lds16(BT + boff + (size_t)r * 2048 + kt + c0s, &Bs[r][c0l]);
    }
    __syncthreads();
#pragma unroll
    for (int kk = 0; kk < 2; ++kk) {
      bf16x8 af[4], bfr[4];
#pragma unroll
      for (int i = 0; i < 4; ++i) {
        const int row = wr + i * 16 + lr;
        af[i] = *(const bf16x8*)&As[row][(((kk << 2) | lq) ^ (row & 7)) << 3];
      }
#pragma unroll
      for (int j = 0; j < 4; ++j) {
        const int row = wc + j * 16 + lr;
        bfr[j] = *(const bf16x8*)&Bs[row][(((kk << 2) | lq) ^ (row & 7)) << 3];
      }
#pragma unroll
      for (int i = 0; i < 4; ++i)
#pragma unroll
        for (int j = 0; j < 4; ++j)
          acc[i][j] = __builtin_amdgcn_mfma_f32_16x16x32_bf16(af[i], bfr[j], acc[i][j], 0, 0, 0);
    }
  }

  float* __restrict__ Pc = P + (size_t)ch * 2097152;
  const int lg4 = lq * 4;
#pragma unroll
  for (int i = 0; i < 4; ++i) {
    const int grow0 = bx * 128 + wr + i * 16 + lg4;
#pragma unroll
    for (int j = 0; j < 4; ++j) {
      const int gcol = byn * 128 + wc + j * 16 + lr;
#pragma unroll
      for (int r = 0; r < 4; ++r)
        Pc[(size_t)(grow0 + r) * 1024 + gcol] = acc[i][j][r];
    }
  }
}

// layer-1 merge: xbf = bf16(p0 + p1)
__global__ __launch_bounds__(256)
void merge_o1(const float* __restrict__ P, u16* __restrict__ xbf) {
  const int i4 = (blockIdx.x * 256 + threadIdx.x) * 4;   // 2048 blocks
  const float4 a = *(const float4*)(P + i4);
  const float4 b = *(const float4*)(P + 2097152 + i4);
  u16x4 o = { f2bf(a.x + b.x), f2bf(a.y + b.y), f2bf(a.z + b.z), f2bf(a.w + b.w) };
  *(u16x4*)(xbf + i4) = o;
}

// layer-2 merge + final LayerNorm fused: xlnbf = bf16(LN(p0+p1))
__global__ __launch_bounds__(256)
void merge_o2_ln(const float* __restrict__ P, const float* __restrict__ g,
                 const float* __restrict__ bta, u16* __restrict__ out) {
  __shared__ float red1[4], red2[4];
  const int r = blockIdx.x;
  const int tid = threadIdx.x;
  const int lane = tid & 63, wid = tid >> 6;
  const int c4 = tid * 4;
  const float4 a = *(const float4*)(P + (size_t)r * 1024 + c4);
  const float4 b = *(const float4*)(P + 2097152 + (size_t)r * 1024 + c4);
  float4 v = { a.x + b.x, a.y + b.y, a.z + b.z, a.w + b.w };
  float s = v.x + v.y + v.z + v.w;
#pragma unroll
  for (int m = 1; m < 64; m <<= 1) s += __shfl_xor(s, m, 64);
  if (lane == 0) red1[wid] = s;
  __syncthreads();
  const float mu = (red1[0] + red1[1] + red1[2] + red1[3]) * (1.f / 1024.f);
  const float d0 = v.x - mu, d1 = v.y - mu, d2 = v.z - mu, d3 = v.w - mu;
  float q = d0 * d0 + d1 * d1 + d2 * d2 + d3 * d3;
#pragma unroll
  for (int m = 1; m < 64; m <<= 1) q += __shfl_xor(q, m, 64);
  if (lane == 0) red2[wid] = q;
  __syncthreads();
  const float rs = rsqrtf((red2[0] + red2[1] + red2[2] + red2[3]) * (1.f / 1024.f) + 1e-5f);
  const float4 gv = *(const float4*)(g + c4);
  const float4 bv = *(const float4*)(bta + c4);
  u16x4 o = { f2bf(d0 * rs * gv.x + bv.x), f2bf(d1 * rs * gv.y + bv.y),
              f2bf(d2 * rs * gv.z + bv.z), f2bf(d3 * rs * gv.w + bv.w) };
  *(u16x4*)(out + (size_t)r * 1024 + c4) = o;
}

// ---------------------------------------------------------------------------
// mega prep batch: up to 10 jobs. tx>=0: transpose f32(K,N)->bf16(Npad,K)
// (NT loads — weights read once per call). tx<0: embed gather (lt = row).
// ---------------------------------------------------------------------------
struct TBatch {
  const float* src[10];
  u16* dst[10];
  int K[10], N[10], tx[10];
  int start[11];
  int njobs;
  const int* ids;
};

__global__ __launch_bounds__(256)
void transpose_batch(TBatch tb) {
  const int tile = blockIdx.x;
  int j = 0;
  while (j + 1 < tb.njobs && tile >= tb.start[j + 1]) ++j;
  const int lt = tile - tb.start[j];

  if (tb.tx[j] < 0) {   // embed gather: row lt, 1024 cols via float4
    const int c = threadIdx.x * 4;
    const int id = tb.ids[lt];
    const float4 v = *(const float4*)(tb.src[j] + (size_t)id * 1024 + c);
    u16x4 o = { f2bf(v.x), f2bf(v.y), f2bf(v.z), f2bf(v.w) };
    *(u16x4*)(tb.dst[j] + (size_t)lt * 1024 + c) = o;
    return;
  }

  const int K = tb.K[j];
  const int N = tb.N[j];
  const int kb = (lt % tb.tx[j]) * 32;
  const int nb = (lt / tb.tx[j]) * 32;
  const float* __restrict__ in = tb.src[j];
  u16* __restrict__ out = tb.dst[j];

  __shared__ float tile_s[32][33];
  const int tx = threadIdx.x & 31;
  const int ty = threadIdx.x >> 5;
#pragma unroll
  for (int s = 0; s < 4; ++s) {
    const int k = kb + ty + s * 8;
    const int n = nb + tx;
    tile_s[ty + s * 8][tx] = (n < N) ? __builtin_nontemporal_load(in + (size_t)k * N + n) : 0.f;
  }
  __syncthreads();
#pragma unroll
  for (int s = 0; s < 4; ++s) {
    const int n = nb + ty + s * 8;
    const int k = kb + tx;
    out[(size_t)n * K + k] = f2bf(tile_s[tx][ty + s * 8]);
  }
}

// u = silu(causal_conv(xin) + cb), 4 channels per thread (float4 path)
__global__ __launch_bounds__(256)
void conv_silu4(const float* __restrict__ xz, const float* __restrict__ cw,
                const float* __restrict__ cb, float* __restrict__ u,
                u16* __restrict__ ubf) {
  const int i4 = (blockIdx.x * 256 + threadIdx.x) * 4;   // grid 4096
  const int d = i4 & 2047;
  const int r = i4 >> 11;
  const int t = r & 1023;
  float4 acc = *(const float4*)(cb + d);
  const float4 w0 = *(const float4*)(cw + (d + 0) * 4);
  const float4 w1 = *(const float4*)(cw + (d + 1) * 4);
  const float4 w2 = *(const float4*)(cw + (d + 2) * 4);
  const float4 w3 = *(const float4*)(cw + (d + 3) * 4);
#pragma unroll
  for (int k = 0; k < 4; ++k) {
    const int tt = t - 3 + k;
    if (tt >= 0) {
      const float4 x4 = *(const float4*)(xz + (size_t)(r - 3 + k) * 4096 + d);
      acc.x = fmaf(x4.x, ((const float*)&w0)[k], acc.x);
      acc.y = fmaf(x4.y, ((const float*)&w1)[k], acc.y);
      acc.z = fmaf(x4.z, ((const float*)&w2)[k], acc.z);
      acc.w = fmaf(x4.w, ((const float*)&w3)[k], acc.w);
    }
  }
  const float4 s = { acc.x / (1.f + __expf(-acc.x)), acc.y / (1.f + __expf(-acc.y)),
                     acc.z / (1.f + __expf(-acc.z)), acc.w / (1.f + __expf(-acc.w)) };
  *(float4*)(u + i4) = s;
  u16x4 o = { f2bf(s.x), f2bf(s.y), f2bf(s.z), f2bf(s.w) };
  *(u16x4*)(ubf + i4) = o;
}

// ---------------------------------------------------------------------------
// chunked selective scan: 8 chunks x 128 steps (pass1 local, pass2 global+y)
// ---------------------------------------------------------------------------
__global__ __launch_bounds__(256)
void scan_pass1(const float* __restrict__ delta, const float* __restrict__ u,
                const float* __restrict__ dbc, const float* __restrict__ A_log,
                float* __restrict__ Pb, float* __restrict__ Qb) {
  const int blk = blockIdx.x;
  const int ch = blk & 7;
  if (ch == 7) return;          // chunk 7's (P,Q) is never consumed
  const int dt16 = (blk >> 3) & 127;
  const int b = blk >> 10;
  const int n = threadIdx.x & 15;
  const int dl = threadIdx.x >> 4;
  const int d = dt16 * 16 + dl;
  const float Ac = -expf(A_log[d * 16 + n]) * 1.44269504f;
  const int r0 = b * 1024 + ch * 128;
  float P = 1.f, h = 0.f;
  for (int j = 0; j < 128; ++j) {
    const size_t r = r0 + j;
    const float dlt = delta[r * 2048 + d];
    const float uu = u[r * 2048 + d];
    const float Bv = dbc[r * 128 + 64 + n];
    const float da = exp2f(dlt * Ac);
    P *= da;
    h = fmaf(da, h, dlt * uu * Bv);
  }
  const size_t idx = ((size_t)(b * 2048 + d) * 16 + n) * 8 + ch;
  Pb[idx] = P;
  Qb[idx] = h;
}

__global__ __launch_bounds__(256)
void scan_pass2(const float* __restrict__ delta, const float* __restrict__ u,
                const float* __restrict__ dbc, const float* __restrict__ xz,
                const float* __restrict__ A_log, const float* __restrict__ Dp,
                const float* __restrict__ Pb, const float* __restrict__ Qb,
                u16* __restrict__ ybf) {
  const int blk = blockIdx.x;
  const int ch = blk & 7;
  const int dt16 = (blk >> 3) & 127;
  const int b = blk >> 10;
  const int n = threadIdx.x & 15;
  const int dl = threadIdx.x >> 4;
  const int d = dt16 * 16 + dl;
  const float Ac = -expf(A_log[d * 16 + n]) * 1.44269504f;
  const float Dd = Dp[d];
  const int r0 = b * 1024 + ch * 128;

  float h = 0.f;
  const size_t p0 = ((size_t)(b * 2048 + d) * 16 + n) * 8;
  for (int cc = 0; cc < ch; ++cc) h = fmaf(Pb[p0 + cc], h, Qb[p0 + cc]);

  for (int j = 0; j < 128; ++j) {
    const size_t r = r0 + j;
    const float dlt = delta[r * 2048 + d];
    const float uu = u[r * 2048 + d];
    const float Bv = dbc[r * 128 + 64 + n];
    const float Cv = dbc[r * 128 + 80 + n];
    const float da = exp2f(dlt * Ac);
    h = fmaf(da, h, dlt * uu * Bv);
    float p = rowsum16(h * Cv);
    if (n == 0) {
      const float zz = xz[r * 4096 + 2048 + d];
      const float yv = (p + uu * Dd) * (zz / (1.f + __expf(-zz)));
      ybf[r * 2048 + d] = f2bf(yv);
    }
  }
}

// ---------------------------------------------------------------------------
extern "C" void kernel_launch(void* const* d_in, const int* in_sizes, int n_in,
                              void* d_out, int out_size, void* d_ws, size_t ws_size,
                              hipStream_t stream) {
  (void)in_sizes; (void)n_in; (void)out_size; (void)ws_size;
  const int*   ids      = (const int*)d_in[0];
  const float* embed    = (const float*)d_in[1];
  const float* in_proj  = (const float*)d_in[2];
  const float* conv_w   = (const float*)d_in[3];
  const float* conv_b   = (const float*)d_in[4];
  const float* x_proj   = (const float*)d_in[5];
  const float* dt_w     = (const float*)d_in[6];
  const float* dt_b     = (const float*)d_in[7];
  const float* A_log    = (const float*)d_in[8];
  const float* Dp       = (const float*)d_in[9];
  const float* out_proj = (const float*)d_in[10];
  const float* ln_g     = (const float*)d_in[11];
  const float* ln_bta   = (const float*)d_in[12];
  const float* head     = (const float*)d_in[13];

  // f32 scratch inside d_out (all consumed before head GEMM overwrites)
  float* fout = (float*)d_out;
  float* xz   = fout;              // 2048*4096
  float* ubuf = fout + 8388608;    // 2048*2048
  float* dbuf = fout + 12582912;   // 2048*2048 (delta)
  float* dbc  = fout + 16777216;   // 2048*128
  float* Pb   = fout + 19136512;   // 524288
  float* Qb   = fout + 19660800;   // 524288
  float* xpp  = fout + 20185088;   // 8 * 2048*128  = 2097152
  float* opp  = fout + 22282240;   // 2 * 2048*1024 = 4194304 (ends 26476544)

  // bf16 weight copies in the dead tail of d_out (dead before head GEMM)
  u16* tail = (u16*)(fout + 27000000);
  u16* WiT[2]  = { tail,                tail + 4194304 };
  u16* WxT[2]  = { tail + 8388608,      tail + 8650752 };
  u16* WdtT[2] = { tail + 8912896,      tail + 9043968 };
  u16* WoT[2]  = { tail + 9175040,      tail + 11272192 };   // ends 13369344 u16

  // bf16 scratch in d_ws (live across / after head GEMM inputs)
  char* wp = (char*)d_ws;
  u16* headT = (u16*)wp; wp += (size_t)32000 * 1024 * 2;
  u16* xbf   = (u16*)wp; wp += (size_t)2048 * 1024 * 2;
  u16* ubf   = (u16*)wp; wp += (size_t)2048 * 2048 * 2;
  u16* dtbf  = (u16*)wp; wp += (size_t)2048 * 64 * 2;
  u16* ybf   = (u16*)wp; wp += (size_t)2048 * 2048 * 2;
  u16* xlnbf = (u16*)wp; wp += (size_t)2048 * 1024 * 2;

  const dim3 tb(256);
  const dim3 tb5(512);

  // ---- one mega prep launch: head + all layer weights + embed gather ----
  TBatch t{};
  int nj = 0, acc = 0;
  t.ids = ids;
  t.src[nj] = head; t.dst[nj] = headT;
  t.K[nj] = 1024; t.N[nj] = 32000; t.tx[nj] = 32;
  t.start[nj] = acc; acc += 32 * 1000; ++nj;
  for (int i = 0; i < 2; ++i) {
    t.src[nj] = in_proj + (size_t)i * 1024 * 4096; t.dst[nj] = WiT[i];
    t.K[nj] = 1024; t.N[nj] = 4096; t.tx[nj] = 32;
    t.start[nj] = acc; acc += 32 * 128; ++nj;
    t.src[nj] = x_proj + (size_t)i * 2048 * 96; t.dst[nj] = WxT[i];
    t.K[nj] = 2048; t.N[nj] = 96; t.tx[nj] = 64;
    t.start[nj] = acc; acc += 64 * 4; ++nj;
    t.src[nj] = dt_w + (size_t)i * 64 * 2048; t.dst[nj] = WdtT[i];
    t.K[nj] = 64; t.N[nj] = 2048; t.tx[nj] = 2;
    t.start[nj] = acc; acc += 2 * 64; ++nj;
    t.src[nj] = out_proj + (size_t)i * 2048 * 1024; t.dst[nj] = WoT[i];
    t.K[nj] = 2048; t.N[nj] = 1024; t.tx[nj] = 64;
    t.start[nj] = acc; acc += 64 * 32; ++nj;
  }
  t.src[nj] = embed; t.dst[nj] = xbf;
  t.K[nj] = 0; t.N[nj] = 0; t.tx[nj] = -1;
  t.start[nj] = acc; acc += 2048; ++nj;
  t.start[nj] = acc;
  t.njobs = nj;
  transpose_batch<<<acc, tb, 0, stream>>>(t);

  for (int i = 0; i < 2; ++i) {
    gemm_bt<0><<<dim3(16, 32), tb, 0, stream>>>(xbf, WiT[i], xz, nullptr, nullptr, 2048, 4096, 1024);
    conv_silu4<<<4096, tb, 0, stream>>>(xz, conv_w + i * 2048 * 4, conv_b + i * 2048, ubuf, ubf);
    xproj_split<<<dim3(16, 8), tb, 0, stream>>>(ubf, WxT[i], xpp);
    merge_x<<<1024, tb, 0, stream>>>(xpp, dbc, dtbf);
    gemm_bt<1><<<dim3(16, 16), tb, 0, stream>>>(dtbf, WdtT[i], dbuf, nullptr, dt_b + i * 2048, 2048, 2048, 64);
    scan_pass1<<<2048, tb, 0, stream>>>(dbuf, ubuf, dbc, A_log + i * 2048 * 16, Pb, Qb);
    scan_pass2<<<2048, tb, 0, stream>>>(dbuf, ubuf, dbc, xz, A_log + i * 2048 * 16, Dp + i * 2048, Pb, Qb, ybf);
    outproj_split<<<dim3(16, 16), tb, 0, stream>>>(ybf, WoT[i], opp);
    if (i == 0) {
      merge_o1<<<2048, tb, 0, stream>>>(opp, xbf);
    } else {
      merge_o2_ln<<<2048, tb, 0, stream>>>(opp, ln_g, ln_bta, xlnbf);
    }
  }

  gemm256<<<dim3(8, 125), tb5, 0, stream>>>(xlnbf, headT, fout, 2048, 32000, 1024);
}